// Round 1
// baseline (4107.777 us; speedup 1.0000x reference)
//
#include <hip/hip_runtime.h>

#define N_NODES 50000
#define N_EDGES 800000
#define NODE_DIM 128
#define C 64
#define N_GRAPHS 512
#define N_LAYERS 5
#define BN_EPS 1e-5f

// ---------------- encoder: h = x @ enc_W + enc_b  [50000,128]x[128,64] ----------------
__global__ __launch_bounds__(256) void enc_kernel(const float* __restrict__ x,
                                                  const float* __restrict__ W,
                                                  const float* __restrict__ b,
                                                  float* __restrict__ h) {
    __shared__ float Ws[NODE_DIM * C];   // 32 KB
    __shared__ float xs[4][NODE_DIM];    // 2 KB
    int t = threadIdx.x;
    for (int i = t; i < NODE_DIM * C; i += 256) Ws[i] = W[i];
    int ch = t & 63, rr = t >> 6;
    float bc = b[ch];
    int row0 = blockIdx.x * 16;
    for (int chunk = 0; chunk < 4; ++chunk) {
        int rowbase = row0 + chunk * 4;
        __syncthreads();  // covers Ws on first iter, xs reuse on later iters
        for (int i = t; i < 4 * NODE_DIM; i += 256)
            xs[i >> 7][i & 127] = x[(rowbase + (i >> 7)) * NODE_DIM + (i & 127)];
        __syncthreads();
        float acc = bc;
#pragma unroll 8
        for (int k = 0; k < NODE_DIM; ++k)
            acc = fmaf(xs[rr][k], Ws[k * C + ch], acc);
        h[(rowbase + rr) * C + ch] = acc;
    }
}

// ---------------- edge aggregation: agg[dst] += h[src] ----------------
__global__ __launch_bounds__(256) void edge_kernel(const int* __restrict__ ei,
                                                   const float* __restrict__ h,
                                                   float* __restrict__ agg) {
    int tid = blockIdx.x * 256 + threadIdx.x;  // N_EDGES*16 threads
    int e = tid >> 4, q = tid & 15;
    if (e >= N_EDGES) return;
    int src = ei[e];
    int dst = ei[N_EDGES + e];
    const float4 v = *(const float4*)(h + src * C + q * 4);
    float* p = agg + dst * C + q * 4;
    atomicAdd(p + 0, v.x);
    atomicAdd(p + 1, v.y);
    atomicAdd(p + 2, v.z);
    atomicAdd(p + 3, v.w);
}

// ---------------- fused GIN MLP: z = relu(relu((h+agg)@W1+b1)@W2+b2), + BN partial stats ----------------
__global__ __launch_bounds__(256) void mlp_kernel(const float* __restrict__ h,
                                                  float* __restrict__ agg,   // in: agg, out: z
                                                  const float* __restrict__ W1,
                                                  const float* __restrict__ b1,
                                                  const float* __restrict__ W2,
                                                  const float* __restrict__ b2,
                                                  float* __restrict__ stats) {
    __shared__ float W1s[C * C];   // 16 KB
    __shared__ float W2s[C * C];   // 16 KB
    __shared__ float ins[4][C];
    __shared__ float t1s[4][C];
    __shared__ float red[256];
    int t = threadIdx.x;
    for (int i = t; i < C * C; i += 256) { W1s[i] = W1[i]; W2s[i] = W2[i]; }
    int ch = t & 63, rr = t >> 6;
    float b1c = b1[ch], b2c = b2[ch];
    int row0 = blockIdx.x * 16;
    float lsum = 0.f, lsq = 0.f;
    for (int chunk = 0; chunk < 4; ++chunk) {
        int row = row0 + chunk * 4 + rr;
        __syncthreads();
        ins[rr][ch] = h[row * C + ch] + agg[row * C + ch];
        __syncthreads();
        float a1 = b1c;
#pragma unroll 8
        for (int k = 0; k < C; ++k) a1 = fmaf(ins[rr][k], W1s[k * C + ch], a1);
        a1 = fmaxf(a1, 0.f);
        t1s[rr][ch] = a1;
        __syncthreads();
        float a2 = b2c;
#pragma unroll 8
        for (int k = 0; k < C; ++k) a2 = fmaf(t1s[rr][k], W2s[k * C + ch], a2);
        a2 = fmaxf(a2, 0.f);
        agg[row * C + ch] = a2;
        lsum += a2;
        lsq += a2 * a2;
    }
    __syncthreads();
    red[t] = lsum;
    __syncthreads();
    if (t < 64) {
        float s = red[t] + red[t + 64] + red[t + 128] + red[t + 192];
        atomicAdd(&stats[t], s);
    }
    __syncthreads();
    red[t] = lsq;
    __syncthreads();
    if (t < 64) {
        float s = red[t] + red[t + 64] + red[t + 128] + red[t + 192];
        atomicAdd(&stats[C + t], s);
    }
}

// ---------------- BN finalize: scale/shift from sums ----------------
__global__ void bn_finalize(const float* __restrict__ stats,
                            const float* __restrict__ gamma,
                            const float* __restrict__ beta,
                            float* __restrict__ ss) {
    int c = threadIdx.x;
    if (c >= C) return;
    const float invN = 1.0f / (float)N_NODES;
    float mean = stats[c] * invN;
    float var = stats[C + c] * invN - mean * mean;
    float rstd = rsqrtf(var + BN_EPS);
    float sc = gamma[c] * rstd;
    ss[c] = sc;
    ss[C + c] = beta[c] - mean * sc;
}

// ---------------- BN apply: h = z * scale + shift ----------------
__global__ __launch_bounds__(256) void bn_apply(const float* __restrict__ z,
                                                const float* __restrict__ ss,
                                                float* __restrict__ h) {
    __shared__ float scs[C], shs[C];
    int t = threadIdx.x;
    if (t < C) { scs[t] = ss[t]; shs[t] = ss[C + t]; }
    __syncthreads();
    int i4 = blockIdx.x * 256 + t;  // over N*C/4 float4s
    if (i4 < N_NODES * C / 4) {
        float4 v = ((const float4*)z)[i4];
        int cb = (i4 & 15) << 2;
        v.x = fmaf(v.x, scs[cb + 0], shs[cb + 0]);
        v.y = fmaf(v.y, scs[cb + 1], shs[cb + 1]);
        v.z = fmaf(v.z, scs[cb + 2], shs[cb + 2]);
        v.w = fmaf(v.w, scs[cb + 3], shs[cb + 3]);
        ((float4*)h)[i4] = v;
    }
}

// ---------------- global add pool: g[batch[n]] += h[n] ----------------
__global__ __launch_bounds__(256) void pool_kernel(const float* __restrict__ h,
                                                   const int* __restrict__ batch,
                                                   float* __restrict__ g) {
    int tid = blockIdx.x * 256 + threadIdx.x;  // N_NODES*16 threads
    int n = tid >> 4, q = tid & 15;
    if (n >= N_NODES) return;
    int b = batch[n];
    float4 v = *(const float4*)(h + n * C + q * 4);
    float* p = g + b * C + q * 4;
    atomicAdd(p + 0, v.x);
    atomicAdd(p + 1, v.y);
    atomicAdd(p + 2, v.z);
    atomicAdd(p + 3, v.w);
}

// ---------------- head: out = relu(g@fc1+b1) @ fc2 + b2 ----------------
__global__ __launch_bounds__(256) void head_kernel(const float* __restrict__ g,
                                                   const float* __restrict__ fc1W,
                                                   const float* __restrict__ fc1b,
                                                   const float* __restrict__ fc2W,
                                                   const float* __restrict__ fc2b,
                                                   float* __restrict__ out) {
    __shared__ float W1s[C * C];    // 16 KB
    __shared__ float W2s[C * 16];   // 4 KB
    __shared__ float gs[4][C], t1s[4][C];
    int t = threadIdx.x;
    for (int i = t; i < C * C; i += 256) W1s[i] = fc1W[i];
    for (int i = t; i < C * 16; i += 256) W2s[i] = fc2W[i];
    int ch = t & 63, rr = t >> 6;
    int g0 = blockIdx.x * 4;
    gs[rr][ch] = g[(g0 + rr) * C + ch];
    __syncthreads();
    float a1 = fc1b[ch];
#pragma unroll 8
    for (int k = 0; k < C; ++k) a1 = fmaf(gs[rr][k], W1s[k * C + ch], a1);
    t1s[rr][ch] = fmaxf(a1, 0.f);
    __syncthreads();
    if (t < 64) {
        int o = t & 15, r2 = t >> 4;
        float a2 = fc2b[o];
#pragma unroll 8
        for (int k = 0; k < C; ++k) a2 = fmaf(t1s[r2][k], W2s[k * 16 + o], a2);
        out[(g0 + r2) * 16 + o] = a2;
    }
}

extern "C" void kernel_launch(void* const* d_in, const int* in_sizes, int n_in,
                              void* d_out, int out_size, void* d_ws, size_t ws_size,
                              hipStream_t stream) {
    const float* x    = (const float*)d_in[0];
    const int*   ei   = (const int*)d_in[1];
    const int*   batch= (const int*)d_in[2];
    const float* encW = (const float*)d_in[3];
    const float* encb = (const float*)d_in[4];
    const float* cW1  = (const float*)d_in[5];
    const float* cb1  = (const float*)d_in[6];
    const float* cW2  = (const float*)d_in[7];
    const float* cb2  = (const float*)d_in[8];
    const float* gam  = (const float*)d_in[9];
    const float* bet  = (const float*)d_in[10];
    const float* f1W  = (const float*)d_in[11];
    const float* f1b  = (const float*)d_in[12];
    const float* f2W  = (const float*)d_in[13];
    const float* f2b  = (const float*)d_in[14];
    float* out = (float*)d_out;

    char* ws = (char*)d_ws;
    float* h     = (float*)(ws);                        // 12.8 MB
    float* agg   = (float*)(ws + 12800000);             // 12.8 MB (also holds z)
    float* stats = (float*)(ws + 25600000);             // 512 B
    float* ss    = (float*)(ws + 25600512);             // 512 B
    float* gpool = (float*)(ws + 25601024);             // 128 KB

    enc_kernel<<<N_NODES / 16, 256, 0, stream>>>(x, encW, encb, h);

    for (int l = 0; l < N_LAYERS; ++l) {
        hipMemsetAsync(agg, 0, (size_t)N_NODES * C * sizeof(float), stream);
        hipMemsetAsync(stats, 0, 2 * C * sizeof(float), stream);
        edge_kernel<<<(N_EDGES * 16) / 256, 256, 0, stream>>>(ei, h, agg);
        mlp_kernel<<<N_NODES / 16, 256, 0, stream>>>(h, agg,
                                                     cW1 + (size_t)l * C * C, cb1 + (size_t)l * C,
                                                     cW2 + (size_t)l * C * C, cb2 + (size_t)l * C,
                                                     stats);
        bn_finalize<<<1, 64, 0, stream>>>(stats, gam + (size_t)l * C, bet + (size_t)l * C, ss);
        bn_apply<<<(N_NODES * C / 4) / 256, 256, 0, stream>>>(agg, ss, h);
    }

    hipMemsetAsync(gpool, 0, (size_t)N_GRAPHS * C * sizeof(float), stream);
    pool_kernel<<<(N_NODES * 16 + 255) / 256, 256, 0, stream>>>(h, batch, gpool);
    head_kernel<<<N_GRAPHS / 4, 256, 0, stream>>>(gpool, f1W, f1b, f2W, f2b, out);
}

// Round 2
// 992.157 us; speedup vs baseline: 4.1402x; 4.1402x over previous
//
#include <hip/hip_runtime.h>

#define N_NODES 50000
#define N_EDGES 800000
#define NODE_DIM 128
#define C 64
#define N_GRAPHS 512
#define N_LAYERS 5
#define BN_EPS 1e-5f

#define SCAN_BLOCKS 196  // ceil(50000/256)

// ---------------- encoder: h = x @ enc_W + enc_b  [50000,128]x[128,64] ----------------
__global__ __launch_bounds__(256) void enc_kernel(const float* __restrict__ x,
                                                  const float* __restrict__ W,
                                                  const float* __restrict__ b,
                                                  float* __restrict__ h) {
    __shared__ float Ws[NODE_DIM * C];   // 32 KB
    __shared__ float xs[4][NODE_DIM];    // 2 KB
    int t = threadIdx.x;
    for (int i = t; i < NODE_DIM * C; i += 256) Ws[i] = W[i];
    int ch = t & 63, rr = t >> 6;
    float bc = b[ch];
    int row0 = blockIdx.x * 16;
    for (int chunk = 0; chunk < 4; ++chunk) {
        int rowbase = row0 + chunk * 4;
        __syncthreads();
        for (int i = t; i < 4 * NODE_DIM; i += 256)
            xs[i >> 7][i & 127] = x[(rowbase + (i >> 7)) * NODE_DIM + (i & 127)];
        __syncthreads();
        float acc = bc;
#pragma unroll 8
        for (int k = 0; k < NODE_DIM; ++k)
            acc = fmaf(xs[rr][k], Ws[k * C + ch], acc);
        h[(rowbase + rr) * C + ch] = acc;
    }
}

// ================= CSR build =================
__global__ __launch_bounds__(256) void deg_kernel(const int* __restrict__ ei,
                                                  int* __restrict__ deg) {
    int e = blockIdx.x * 256 + threadIdx.x;
    if (e < N_EDGES) atomicAdd(&deg[ei[N_EDGES + e]], 1);
}

// k1: per-chunk inclusive scan of deg -> offs[i+1]; chunk totals -> partials
__global__ __launch_bounds__(256) void scan_k1(const int* __restrict__ deg,
                                               int* __restrict__ offs,
                                               int* __restrict__ partials) {
    __shared__ int s[256];
    int t = threadIdx.x;
    int i = blockIdx.x * 256 + t;
    int v = (i < N_NODES) ? deg[i] : 0;
    s[t] = v;
    for (int off = 1; off < 256; off <<= 1) {
        __syncthreads();
        int x = (t >= off) ? s[t - off] : 0;
        __syncthreads();
        s[t] += x;
    }
    __syncthreads();
    if (i < N_NODES) offs[i + 1] = s[t];
    if (t == 255) partials[blockIdx.x] = s[255];
}

// k2: exclusive scan of partials (single block)
__global__ __launch_bounds__(256) void scan_k2(int* __restrict__ partials) {
    __shared__ int s[256];
    int t = threadIdx.x;
    int v = (t < SCAN_BLOCKS) ? partials[t] : 0;
    s[t] = v;
    for (int off = 1; off < 256; off <<= 1) {
        __syncthreads();
        int x = (t >= off) ? s[t - off] : 0;
        __syncthreads();
        s[t] += x;
    }
    __syncthreads();
    if (t < SCAN_BLOCKS) partials[t] = s[t] - v;  // exclusive
}

// k3: offs[i+1] += partials[b] (private RMW); cursor = offs
__global__ __launch_bounds__(256) void scan_k3(const int* __restrict__ partials,
                                               int* __restrict__ offs,
                                               int* __restrict__ cursor) {
    int t = threadIdx.x;
    int i = blockIdx.x * 256 + t;
    if (i < N_NODES) {
        int v = offs[i + 1] + partials[blockIdx.x];
        offs[i + 1] = v;
        cursor[i + 1] = v;
    }
    if (i == 0) { offs[0] = 0; cursor[0] = 0; }
}

__global__ __launch_bounds__(256) void scatter_kernel(const int* __restrict__ ei,
                                                      int* __restrict__ cursor,
                                                      int* __restrict__ csr_src) {
    int e = blockIdx.x * 256 + threadIdx.x;
    if (e >= N_EDGES) return;
    int src = ei[e];
    int dst = ei[N_EDGES + e];
    int pos = atomicAdd(&cursor[dst], 1);
    csr_src[pos] = src;
}

// ---------------- gather: z[n] = h[n] + sum_{e in CSR[n]} h[src(e)] ----------------
__global__ __launch_bounds__(256) void gather_kernel(const int* __restrict__ csr_src,
                                                     const int* __restrict__ offs,
                                                     const float* __restrict__ h,
                                                     float* __restrict__ z) {
    int t = threadIdx.x;
    int node = blockIdx.x * 16 + (t >> 4);
    int q = t & 15;
    const float4* h4 = (const float4*)h;
    int beg = offs[node], end = offs[node + 1];
    float4 acc = h4[node * 16 + q];  // self term (GIN eps=0)
    for (int e = beg; e < end; ++e) {
        int s = csr_src[e];
        float4 v = h4[s * 16 + q];
        acc.x += v.x; acc.y += v.y; acc.z += v.z; acc.w += v.w;
    }
    ((float4*)z)[node * 16 + q] = acc;
}

// ---------------- fused GIN MLP + BN partial stats ----------------
__global__ __launch_bounds__(256) void mlp_kernel(float* __restrict__ z,   // in: z, out: z2 (in place)
                                                  const float* __restrict__ W1,
                                                  const float* __restrict__ b1,
                                                  const float* __restrict__ W2,
                                                  const float* __restrict__ b2,
                                                  float* __restrict__ stats) {
    __shared__ float W1s[C * C];
    __shared__ float W2s[C * C];
    __shared__ float ins[4][C];
    __shared__ float t1s[4][C];
    __shared__ float red[256];
    int t = threadIdx.x;
    for (int i = t; i < C * C; i += 256) { W1s[i] = W1[i]; W2s[i] = W2[i]; }
    int ch = t & 63, rr = t >> 6;
    float b1c = b1[ch], b2c = b2[ch];
    int row0 = blockIdx.x * 16;
    float lsum = 0.f, lsq = 0.f;
    for (int chunk = 0; chunk < 4; ++chunk) {
        int row = row0 + chunk * 4 + rr;
        __syncthreads();
        ins[rr][ch] = z[row * C + ch];
        __syncthreads();
        float a1 = b1c;
#pragma unroll 8
        for (int k = 0; k < C; ++k) a1 = fmaf(ins[rr][k], W1s[k * C + ch], a1);
        a1 = fmaxf(a1, 0.f);
        t1s[rr][ch] = a1;
        __syncthreads();
        float a2 = b2c;
#pragma unroll 8
        for (int k = 0; k < C; ++k) a2 = fmaf(t1s[rr][k], W2s[k * C + ch], a2);
        a2 = fmaxf(a2, 0.f);
        z[row * C + ch] = a2;
        lsum += a2;
        lsq += a2 * a2;
    }
    __syncthreads();
    red[t] = lsum;
    __syncthreads();
    if (t < 64) {
        float s = red[t] + red[t + 64] + red[t + 128] + red[t + 192];
        atomicAdd(&stats[t], s);
    }
    __syncthreads();
    red[t] = lsq;
    __syncthreads();
    if (t < 64) {
        float s = red[t] + red[t + 64] + red[t + 128] + red[t + 192];
        atomicAdd(&stats[C + t], s);
    }
}

// ---------------- BN finalize ----------------
__global__ void bn_finalize(const float* __restrict__ stats,
                            const float* __restrict__ gamma,
                            const float* __restrict__ beta,
                            float* __restrict__ ss) {
    int c = threadIdx.x;
    if (c >= C) return;
    const float invN = 1.0f / (float)N_NODES;
    float mean = stats[c] * invN;
    float var = stats[C + c] * invN - mean * mean;
    float rstd = rsqrtf(var + BN_EPS);
    float sc = gamma[c] * rstd;
    ss[c] = sc;
    ss[C + c] = beta[c] - mean * sc;
}

// ---------------- BN apply: h = z * scale + shift ----------------
__global__ __launch_bounds__(256) void bn_apply(const float* __restrict__ z,
                                                const float* __restrict__ ss,
                                                float* __restrict__ h) {
    __shared__ float scs[C], shs[C];
    int t = threadIdx.x;
    if (t < C) { scs[t] = ss[t]; shs[t] = ss[C + t]; }
    __syncthreads();
    int i4 = blockIdx.x * 256 + t;
    if (i4 < N_NODES * C / 4) {
        float4 v = ((const float4*)z)[i4];
        int cb = (i4 & 15) << 2;
        v.x = fmaf(v.x, scs[cb + 0], shs[cb + 0]);
        v.y = fmaf(v.y, scs[cb + 1], shs[cb + 1]);
        v.z = fmaf(v.z, scs[cb + 2], shs[cb + 2]);
        v.w = fmaf(v.w, scs[cb + 3], shs[cb + 3]);
        ((float4*)h)[i4] = v;
    }
}

// ---------------- global add pool ----------------
__global__ __launch_bounds__(256) void pool_kernel(const float* __restrict__ h,
                                                   const int* __restrict__ batch,
                                                   float* __restrict__ g) {
    int tid = blockIdx.x * 256 + threadIdx.x;
    int n = tid >> 4, q = tid & 15;
    if (n >= N_NODES) return;
    int b = batch[n];
    float4 v = *(const float4*)(h + n * C + q * 4);
    float* p = g + b * C + q * 4;
    atomicAdd(p + 0, v.x);
    atomicAdd(p + 1, v.y);
    atomicAdd(p + 2, v.z);
    atomicAdd(p + 3, v.w);
}

// ---------------- head ----------------
__global__ __launch_bounds__(256) void head_kernel(const float* __restrict__ g,
                                                   const float* __restrict__ fc1W,
                                                   const float* __restrict__ fc1b,
                                                   const float* __restrict__ fc2W,
                                                   const float* __restrict__ fc2b,
                                                   float* __restrict__ out) {
    __shared__ float W1s[C * C];
    __shared__ float W2s[C * 16];
    __shared__ float gs[4][C], t1s[4][C];
    int t = threadIdx.x;
    for (int i = t; i < C * C; i += 256) W1s[i] = fc1W[i];
    for (int i = t; i < C * 16; i += 256) W2s[i] = fc2W[i];
    int ch = t & 63, rr = t >> 6;
    int g0 = blockIdx.x * 4;
    gs[rr][ch] = g[(g0 + rr) * C + ch];
    __syncthreads();
    float a1 = fc1b[ch];
#pragma unroll 8
    for (int k = 0; k < C; ++k) a1 = fmaf(gs[rr][k], W1s[k * C + ch], a1);
    t1s[rr][ch] = fmaxf(a1, 0.f);
    __syncthreads();
    if (t < 64) {
        int o = t & 15, r2 = t >> 4;
        float a2 = fc2b[o];
#pragma unroll 8
        for (int k = 0; k < C; ++k) a2 = fmaf(t1s[r2][k], W2s[k * 16 + o], a2);
        out[(g0 + r2) * 16 + o] = a2;
    }
}

extern "C" void kernel_launch(void* const* d_in, const int* in_sizes, int n_in,
                              void* d_out, int out_size, void* d_ws, size_t ws_size,
                              hipStream_t stream) {
    const float* x    = (const float*)d_in[0];
    const int*   ei   = (const int*)d_in[1];
    const int*   batch= (const int*)d_in[2];
    const float* encW = (const float*)d_in[3];
    const float* encb = (const float*)d_in[4];
    const float* cW1  = (const float*)d_in[5];
    const float* cb1  = (const float*)d_in[6];
    const float* cW2  = (const float*)d_in[7];
    const float* cb2  = (const float*)d_in[8];
    const float* gam  = (const float*)d_in[9];
    const float* bet  = (const float*)d_in[10];
    const float* f1W  = (const float*)d_in[11];
    const float* f1b  = (const float*)d_in[12];
    const float* f2W  = (const float*)d_in[13];
    const float* f2b  = (const float*)d_in[14];
    float* out = (float*)d_out;

    char* ws = (char*)d_ws;
    float* h       = (float*)(ws);                    // 12.8 MB
    float* z       = (float*)(ws + 12800000);         // 12.8 MB
    int*   csr     = (int*)  (ws + 25600000);         // 3.2 MB
    int*   offs    = (int*)  (ws + 28800000);         // 200,064 B
    int*   deg     = (int*)  (ws + 29000064);         // 200,000 B
    int*   cursor  = (int*)  (ws + 29200064);         // 200,064 B
    int*   partials= (int*)  (ws + 29400128);         // 1 KB
    float* stats   = (float*)(ws + 29401152);         // 512 B
    float* ssb     = (float*)(ws + 29401664);         // 512 B
    float* gpool   = (float*)(ws + 29402176);         // 128 KB

    // --- CSR build (once per call) ---
    hipMemsetAsync(deg, 0, (size_t)N_NODES * sizeof(int), stream);
    deg_kernel<<<(N_EDGES + 255) / 256, 256, 0, stream>>>(ei, deg);
    scan_k1<<<SCAN_BLOCKS, 256, 0, stream>>>(deg, offs, partials);
    scan_k2<<<1, 256, 0, stream>>>(partials);
    scan_k3<<<SCAN_BLOCKS, 256, 0, stream>>>(partials, offs, cursor);
    scatter_kernel<<<(N_EDGES + 255) / 256, 256, 0, stream>>>(ei, cursor, csr);

    enc_kernel<<<N_NODES / 16, 256, 0, stream>>>(x, encW, encb, h);

    for (int l = 0; l < N_LAYERS; ++l) {
        hipMemsetAsync(stats, 0, 2 * C * sizeof(float), stream);
        gather_kernel<<<N_NODES / 16, 256, 0, stream>>>(csr, offs, h, z);
        mlp_kernel<<<N_NODES / 16, 256, 0, stream>>>(z,
                                                     cW1 + (size_t)l * C * C, cb1 + (size_t)l * C,
                                                     cW2 + (size_t)l * C * C, cb2 + (size_t)l * C,
                                                     stats);
        bn_finalize<<<1, 64, 0, stream>>>(stats, gam + (size_t)l * C, bet + (size_t)l * C, ssb);
        bn_apply<<<(N_NODES * C / 4) / 256, 256, 0, stream>>>(z, ssb, h);
    }

    hipMemsetAsync(gpool, 0, (size_t)N_GRAPHS * C * sizeof(float), stream);
    pool_kernel<<<(N_NODES * 16 + 255) / 256, 256, 0, stream>>>(h, batch, gpool);
    head_kernel<<<N_GRAPHS / 4, 256, 0, stream>>>(gpool, f1W, f1b, f2W, f2b, out);
}

// Round 3
// 617.969 us; speedup vs baseline: 6.6472x; 1.6055x over previous
//
#include <hip/hip_runtime.h>

#define N_NODES 50000
#define N_EDGES 800000
#define NODE_DIM 128
#define C 64
#define N_GRAPHS 512
#define N_LAYERS 5
#define BN_EPS 1e-5f

#define SCAN_BLOCKS 196  // ceil(50000/256)
#define BM 128           // rows per MLP block

// =============================================================
// encoder: h = x @ enc_W + enc_b   [50000,128]x[128,64]
// register-tiled: 256 thr = 16 tc x 16 tr, TM=8 rows, TN=4 cols
// K=128 staged in 2 chunks of 64 (LDS budget)
// =============================================================
__global__ __launch_bounds__(256) void enc_kernel(const float* __restrict__ x,
                                                  const float* __restrict__ W,
                                                  const float* __restrict__ b,
                                                  float* __restrict__ z) {
    __shared__ float As[64 * 132];        // [k][row], row-dim padded to 132
    __shared__ float Ws[NODE_DIM * C];    // 32 KB, full K
    int t = threadIdx.x;
    int tc = t & 15, tr = t >> 4;
    for (int i = t; i < NODE_DIM * C; i += 256) Ws[i] = W[i];
    int row0 = blockIdx.x * BM;
    float4 bv = ((const float4*)b)[tc];
    float acc[8][4];
#pragma unroll
    for (int i = 0; i < 8; ++i) { acc[i][0] = bv.x; acc[i][1] = bv.y; acc[i][2] = bv.z; acc[i][3] = bv.w; }

    for (int kc = 0; kc < 2; ++kc) {
        __syncthreads();
        // stage x[:, kc*64 .. +63]^T into As
        for (int it = 0; it < 8; ++it) {
            int idx = t + 256 * it;            // 0..2047
            int r = idx >> 4, f4 = idx & 15;   // f4: which float4 of the 64-col chunk
            int grow = row0 + r;
            float4 v = (grow < N_NODES) ? ((const float4*)x)[grow * 32 + kc * 16 + f4]
                                        : make_float4(0.f, 0.f, 0.f, 0.f);
            int k4 = f4 * 4;
            As[(k4 + 0) * 132 + r] = v.x;
            As[(k4 + 1) * 132 + r] = v.y;
            As[(k4 + 2) * 132 + r] = v.z;
            As[(k4 + 3) * 132 + r] = v.w;
        }
        __syncthreads();
#pragma unroll 4
        for (int k = 0; k < 64; ++k) {
            const float* ap = As + k * 132 + tr * 8;
            float4 a0 = *(const float4*)(ap);
            float4 a1 = *(const float4*)(ap + 4);
            float4 w = *(const float4*)(Ws + (kc * 64 + k) * C + tc * 4);
            float av[8] = {a0.x, a0.y, a0.z, a0.w, a1.x, a1.y, a1.z, a1.w};
#pragma unroll
            for (int i = 0; i < 8; ++i) {
                acc[i][0] = fmaf(av[i], w.x, acc[i][0]);
                acc[i][1] = fmaf(av[i], w.y, acc[i][1]);
                acc[i][2] = fmaf(av[i], w.z, acc[i][2]);
                acc[i][3] = fmaf(av[i], w.w, acc[i][3]);
            }
        }
    }
#pragma unroll
    for (int i = 0; i < 8; ++i) {
        int grow = row0 + tr * 8 + i;
        if (grow < N_NODES) {
            float4 o = make_float4(acc[i][0], acc[i][1], acc[i][2], acc[i][3]);
            ((float4*)z)[grow * 16 + tc] = o;
        }
    }
}

// ================= CSR build =================
__global__ __launch_bounds__(256) void deg_kernel(const int* __restrict__ ei,
                                                  int* __restrict__ deg) {
    int e = blockIdx.x * 256 + threadIdx.x;
    if (e < N_EDGES) atomicAdd(&deg[ei[N_EDGES + e]], 1);
}

__global__ __launch_bounds__(256) void scan_k1(const int* __restrict__ deg,
                                               int* __restrict__ offs,
                                               int* __restrict__ partials) {
    __shared__ int s[256];
    int t = threadIdx.x;
    int i = blockIdx.x * 256 + t;
    int v = (i < N_NODES) ? deg[i] : 0;
    s[t] = v;
    for (int off = 1; off < 256; off <<= 1) {
        __syncthreads();
        int x = (t >= off) ? s[t - off] : 0;
        __syncthreads();
        s[t] += x;
    }
    __syncthreads();
    if (i < N_NODES) offs[i + 1] = s[t];
    if (t == 255) partials[blockIdx.x] = s[255];
}

__global__ __launch_bounds__(256) void scan_k2(int* __restrict__ partials) {
    __shared__ int s[256];
    int t = threadIdx.x;
    int v = (t < SCAN_BLOCKS) ? partials[t] : 0;
    s[t] = v;
    for (int off = 1; off < 256; off <<= 1) {
        __syncthreads();
        int x = (t >= off) ? s[t - off] : 0;
        __syncthreads();
        s[t] += x;
    }
    __syncthreads();
    if (t < SCAN_BLOCKS) partials[t] = s[t] - v;  // exclusive
}

__global__ __launch_bounds__(256) void scan_k3(const int* __restrict__ partials,
                                               int* __restrict__ offs,
                                               int* __restrict__ cursor) {
    int t = threadIdx.x;
    int i = blockIdx.x * 256 + t;
    if (i < N_NODES) {
        int v = offs[i + 1] + partials[blockIdx.x];
        offs[i + 1] = v;
        cursor[i + 1] = v;
    }
    if (i == 0) { offs[0] = 0; cursor[0] = 0; }
}

__global__ __launch_bounds__(256) void scatter_kernel(const int* __restrict__ ei,
                                                      int* __restrict__ cursor,
                                                      int* __restrict__ csr_src) {
    int e = blockIdx.x * 256 + threadIdx.x;
    if (e >= N_EDGES) return;
    int src = ei[e];
    int dst = ei[N_EDGES + e];
    int pos = atomicAdd(&cursor[dst], 1);
    csr_src[pos] = src;
}

// =============================================================
// fused BN-apply + gather:
// y[n] = sc*(z[n] + sum_{src} z[src]) + (deg+1)*sh
// (since h = z*sc+sh, and sum of affine terms factors out)
// use_ss=0 -> identity (layer 0, encoder output)
// =============================================================
__global__ __launch_bounds__(256) void gather_kernel(const int* __restrict__ csr_src,
                                                     const int* __restrict__ offs,
                                                     const float* __restrict__ z,
                                                     const float* __restrict__ ss,
                                                     int use_ss,
                                                     float* __restrict__ y) {
    int t = threadIdx.x;
    int node = blockIdx.x * 16 + (t >> 4);
    int q = t & 15;
    float4 sc = make_float4(1.f, 1.f, 1.f, 1.f);
    float4 sh = make_float4(0.f, 0.f, 0.f, 0.f);
    if (use_ss) {
        sc = ((const float4*)ss)[q];
        sh = ((const float4*)(ss + C))[q];
    }
    const float4* z4 = (const float4*)z;
    int beg = offs[node], end = offs[node + 1];
    float4 acc = z4[node * 16 + q];  // self term (GIN eps=0)
    for (int e = beg; e < end; ++e) {
        int s = csr_src[e];
        float4 v = z4[s * 16 + q];
        acc.x += v.x; acc.y += v.y; acc.z += v.z; acc.w += v.w;
    }
    float cnt = (float)(end - beg + 1);
    float4 o;
    o.x = fmaf(acc.x, sc.x, cnt * sh.x);
    o.y = fmaf(acc.y, sc.y, cnt * sh.y);
    o.z = fmaf(acc.z, sc.z, cnt * sh.z);
    o.w = fmaf(acc.w, sc.w, cnt * sh.w);
    ((float4*)y)[node * 16 + q] = o;
}

// =============================================================
// fused GIN MLP: z = relu(relu(y@W1+b1)@W2+b2) + BN partial stats
// register-tiled: BM=128, 256 thr = 16 tc x 16 tr, TM=8, TN=4
// =============================================================
__global__ __launch_bounds__(256) void mlp_kernel(const float* __restrict__ y,
                                                  float* __restrict__ z,
                                                  const float* __restrict__ W1,
                                                  const float* __restrict__ b1,
                                                  const float* __restrict__ W2,
                                                  const float* __restrict__ b2,
                                                  float* __restrict__ stats) {
    __shared__ float As[64 * 132];   // [k][row] padded — reused for t1
    __shared__ float W1s[C * C];
    __shared__ float W2s[C * C];
    int t = threadIdx.x;
    int tc = t & 15, tr = t >> 4;
    for (int i = t; i < C * C; i += 256) { W1s[i] = W1[i]; W2s[i] = W2[i]; }
    int row0 = blockIdx.x * BM;

    // ---- stage y^T into As ----
    for (int it = 0; it < 8; ++it) {
        int idx = t + 256 * it;
        int r = idx >> 4, f4 = idx & 15;
        int grow = row0 + r;
        float4 v = (grow < N_NODES) ? ((const float4*)y)[grow * 16 + f4]
                                    : make_float4(0.f, 0.f, 0.f, 0.f);
        int k4 = f4 * 4;
        As[(k4 + 0) * 132 + r] = v.x;
        As[(k4 + 1) * 132 + r] = v.y;
        As[(k4 + 2) * 132 + r] = v.z;
        As[(k4 + 3) * 132 + r] = v.w;
    }
    __syncthreads();

    // ---- GEMM1: t1 = relu(y@W1+b1) ----
    float4 b1v = ((const float4*)b1)[tc];
    float acc[8][4];
#pragma unroll
    for (int i = 0; i < 8; ++i) { acc[i][0] = b1v.x; acc[i][1] = b1v.y; acc[i][2] = b1v.z; acc[i][3] = b1v.w; }
#pragma unroll 4
    for (int k = 0; k < 64; ++k) {
        const float* ap = As + k * 132 + tr * 8;
        float4 a0 = *(const float4*)(ap);
        float4 a1 = *(const float4*)(ap + 4);
        float4 w = *(const float4*)(W1s + k * C + tc * 4);
        float av[8] = {a0.x, a0.y, a0.z, a0.w, a1.x, a1.y, a1.z, a1.w};
#pragma unroll
        for (int i = 0; i < 8; ++i) {
            acc[i][0] = fmaf(av[i], w.x, acc[i][0]);
            acc[i][1] = fmaf(av[i], w.y, acc[i][1]);
            acc[i][2] = fmaf(av[i], w.z, acc[i][2]);
            acc[i][3] = fmaf(av[i], w.w, acc[i][3]);
        }
    }
    __syncthreads();  // all reads of As done

    // ---- restage t1^T into As ----
#pragma unroll
    for (int i = 0; i < 8; ++i)
#pragma unroll
        for (int j = 0; j < 4; ++j)
            As[(tc * 4 + j) * 132 + tr * 8 + i] = fmaxf(acc[i][j], 0.f);
    __syncthreads();

    // ---- GEMM2: z = relu(t1@W2+b2) ----
    float4 b2v = ((const float4*)b2)[tc];
#pragma unroll
    for (int i = 0; i < 8; ++i) { acc[i][0] = b2v.x; acc[i][1] = b2v.y; acc[i][2] = b2v.z; acc[i][3] = b2v.w; }
#pragma unroll 4
    for (int k = 0; k < 64; ++k) {
        const float* ap = As + k * 132 + tr * 8;
        float4 a0 = *(const float4*)(ap);
        float4 a1 = *(const float4*)(ap + 4);
        float4 w = *(const float4*)(W2s + k * C + tc * 4);
        float av[8] = {a0.x, a0.y, a0.z, a0.w, a1.x, a1.y, a1.z, a1.w};
#pragma unroll
        for (int i = 0; i < 8; ++i) {
            acc[i][0] = fmaf(av[i], w.x, acc[i][0]);
            acc[i][1] = fmaf(av[i], w.y, acc[i][1]);
            acc[i][2] = fmaf(av[i], w.z, acc[i][2]);
            acc[i][3] = fmaf(av[i], w.w, acc[i][3]);
        }
    }

    // ---- relu, store, local BN stats ----
    float lsum[4] = {0.f, 0.f, 0.f, 0.f};
    float lsq[4] = {0.f, 0.f, 0.f, 0.f};
#pragma unroll
    for (int i = 0; i < 8; ++i) {
        int grow = row0 + tr * 8 + i;
        if (grow < N_NODES) {
            float4 o;
            o.x = fmaxf(acc[i][0], 0.f);
            o.y = fmaxf(acc[i][1], 0.f);
            o.z = fmaxf(acc[i][2], 0.f);
            o.w = fmaxf(acc[i][3], 0.f);
            ((float4*)z)[grow * 16 + tc] = o;
            lsum[0] += o.x; lsum[1] += o.y; lsum[2] += o.z; lsum[3] += o.w;
            lsq[0] += o.x * o.x; lsq[1] += o.y * o.y; lsq[2] += o.z * o.z; lsq[3] += o.w * o.w;
        }
    }
    // block-reduce stats in W1s (free now): red[16][128]
    __syncthreads();
    float* red = W1s;
#pragma unroll
    for (int j = 0; j < 4; ++j) {
        red[tr * 128 + tc * 4 + j] = lsum[j];
        red[tr * 128 + 64 + tc * 4 + j] = lsq[j];
    }
    __syncthreads();
    if (t < 128) {
        float s = 0.f;
#pragma unroll
        for (int r = 0; r < 16; ++r) s += red[r * 128 + t];
        atomicAdd(&stats[t], s);  // stats[0..63]=sum, [64..127]=sumsq
    }
}

// ---------------- BN finalize ----------------
__global__ void bn_finalize(const float* __restrict__ stats,
                            const float* __restrict__ gamma,
                            const float* __restrict__ beta,
                            float* __restrict__ ss) {
    int c = threadIdx.x;
    if (c >= C) return;
    const float invN = 1.0f / (float)N_NODES;
    float mean = stats[c] * invN;
    float var = stats[C + c] * invN - mean * mean;
    float rstd = rsqrtf(var + BN_EPS);
    float sc = gamma[c] * rstd;
    ss[c] = sc;
    ss[C + c] = beta[c] - mean * sc;
}

// ---------------- global add pool (BN fused): g[batch[n]] += z[n]*sc+sh ----------------
__global__ __launch_bounds__(256) void pool_kernel(const float* __restrict__ z,
                                                   const float* __restrict__ ss,
                                                   const int* __restrict__ batch,
                                                   float* __restrict__ g) {
    int tid = blockIdx.x * 256 + threadIdx.x;
    int n = tid >> 4, q = tid & 15;
    if (n >= N_NODES) return;
    float4 sc = ((const float4*)ss)[q];
    float4 sh = ((const float4*)(ss + C))[q];
    int b = batch[n];
    float4 v = ((const float4*)z)[n * 16 + q];
    float* p = g + b * C + q * 4;
    atomicAdd(p + 0, fmaf(v.x, sc.x, sh.x));
    atomicAdd(p + 1, fmaf(v.y, sc.y, sh.y));
    atomicAdd(p + 2, fmaf(v.z, sc.z, sh.z));
    atomicAdd(p + 3, fmaf(v.w, sc.w, sh.w));
}

// ---------------- head ----------------
__global__ __launch_bounds__(256) void head_kernel(const float* __restrict__ g,
                                                   const float* __restrict__ fc1W,
                                                   const float* __restrict__ fc1b,
                                                   const float* __restrict__ fc2W,
                                                   const float* __restrict__ fc2b,
                                                   float* __restrict__ out) {
    __shared__ float W1s[C * C];
    __shared__ float W2s[C * 16];
    __shared__ float gs[4][C], t1s[4][C];
    int t = threadIdx.x;
    for (int i = t; i < C * C; i += 256) W1s[i] = fc1W[i];
    for (int i = t; i < C * 16; i += 256) W2s[i] = fc2W[i];
    int ch = t & 63, rr = t >> 6;
    int g0 = blockIdx.x * 4;
    gs[rr][ch] = g[(g0 + rr) * C + ch];
    __syncthreads();
    float a1 = fc1b[ch];
#pragma unroll 8
    for (int k = 0; k < C; ++k) a1 = fmaf(gs[rr][k], W1s[k * C + ch], a1);
    t1s[rr][ch] = fmaxf(a1, 0.f);
    __syncthreads();
    if (t < 64) {
        int o = t & 15, r2 = t >> 4;
        float a2 = fc2b[o];
#pragma unroll 8
        for (int k = 0; k < C; ++k) a2 = fmaf(t1s[r2][k], W2s[k * 16 + o], a2);
        out[(g0 + r2) * 16 + o] = a2;
    }
}

extern "C" void kernel_launch(void* const* d_in, const int* in_sizes, int n_in,
                              void* d_out, int out_size, void* d_ws, size_t ws_size,
                              hipStream_t stream) {
    const float* x    = (const float*)d_in[0];
    const int*   ei   = (const int*)d_in[1];
    const int*   batch= (const int*)d_in[2];
    const float* encW = (const float*)d_in[3];
    const float* encb = (const float*)d_in[4];
    const float* cW1  = (const float*)d_in[5];
    const float* cb1  = (const float*)d_in[6];
    const float* cW2  = (const float*)d_in[7];
    const float* cb2  = (const float*)d_in[8];
    const float* gam  = (const float*)d_in[9];
    const float* bet  = (const float*)d_in[10];
    const float* f1W  = (const float*)d_in[11];
    const float* f1b  = (const float*)d_in[12];
    const float* f2W  = (const float*)d_in[13];
    const float* f2b  = (const float*)d_in[14];
    float* out = (float*)d_out;

    char* ws = (char*)d_ws;
    float* z       = (float*)(ws);                    // 12.8 MB
    float* y       = (float*)(ws + 12800000);         // 12.8 MB
    int*   csr     = (int*)  (ws + 25600000);         // 3.2 MB
    int*   offs    = (int*)  (ws + 28800000);         // 200,064 B
    int*   deg     = (int*)  (ws + 29000064);         // 200,000 B
    int*   cursor  = (int*)  (ws + 29200064);         // 200,064 B
    int*   partials= (int*)  (ws + 29400128);         // 1 KB
    float* stats   = (float*)(ws + 29401152);         // 512 B
    float* ssb     = (float*)(ws + 29401664);         // 512 B
    float* gpool   = (float*)(ws + 29402176);         // 128 KB

    // --- CSR build (once per call) ---
    hipMemsetAsync(deg, 0, (size_t)N_NODES * sizeof(int), stream);
    deg_kernel<<<(N_EDGES + 255) / 256, 256, 0, stream>>>(ei, deg);
    scan_k1<<<SCAN_BLOCKS, 256, 0, stream>>>(deg, offs, partials);
    scan_k2<<<1, 256, 0, stream>>>(partials);
    scan_k3<<<SCAN_BLOCKS, 256, 0, stream>>>(partials, offs, cursor);
    scatter_kernel<<<(N_EDGES + 255) / 256, 256, 0, stream>>>(ei, cursor, csr);

    enc_kernel<<<(N_NODES + BM - 1) / BM, 256, 0, stream>>>(x, encW, encb, z);

    for (int l = 0; l < N_LAYERS; ++l) {
        hipMemsetAsync(stats, 0, 2 * C * sizeof(float), stream);
        gather_kernel<<<N_NODES / 16, 256, 0, stream>>>(csr, offs, z, ssb, l > 0 ? 1 : 0, y);
        mlp_kernel<<<(N_NODES + BM - 1) / BM, 256, 0, stream>>>(y, z,
                                                     cW1 + (size_t)l * C * C, cb1 + (size_t)l * C,
                                                     cW2 + (size_t)l * C * C, cb2 + (size_t)l * C,
                                                     stats);
        bn_finalize<<<1, 64, 0, stream>>>(stats, gam + (size_t)l * C, bet + (size_t)l * C, ssb);
    }

    hipMemsetAsync(gpool, 0, (size_t)N_GRAPHS * C * sizeof(float), stream);
    pool_kernel<<<(N_NODES * 16 + 255) / 256, 256, 0, stream>>>(z, ssb, batch, gpool);
    head_kernel<<<N_GRAPHS / 4, 256, 0, stream>>>(gpool, f1W, f1b, f2W, f2b, out);
}

// Round 4
// 589.062 us; speedup vs baseline: 6.9734x; 1.0491x over previous
//
#include <hip/hip_runtime.h>

#define N_NODES 50000
#define N_EDGES 800000
#define NODE_DIM 128
#define C 64
#define N_GRAPHS 512
#define N_LAYERS 5
#define BN_EPS 1e-5f

#define SCAN_BLOCKS 196  // ceil(50000/256)
#define BM 128           // rows per MLP block

// =============================================================
// encoder: h = x @ enc_W + enc_b   [50000,128]x[128,64]
// register-tiled: 256 thr = 16 tc x 16 tr, TM=8 rows, TN=4 cols
// =============================================================
__global__ __launch_bounds__(256) void enc_kernel(const float* __restrict__ x,
                                                  const float* __restrict__ W,
                                                  const float* __restrict__ b,
                                                  float* __restrict__ z) {
    __shared__ float As[64 * 132];        // [k][row], row-dim padded to 132
    __shared__ float Ws[NODE_DIM * C];    // 32 KB, full K
    int t = threadIdx.x;
    int tc = t & 15, tr = t >> 4;
    for (int i = t; i < NODE_DIM * C; i += 256) Ws[i] = W[i];
    int row0 = blockIdx.x * BM;
    float4 bv = ((const float4*)b)[tc];
    float acc[8][4];
#pragma unroll
    for (int i = 0; i < 8; ++i) { acc[i][0] = bv.x; acc[i][1] = bv.y; acc[i][2] = bv.z; acc[i][3] = bv.w; }

    for (int kc = 0; kc < 2; ++kc) {
        __syncthreads();
        for (int it = 0; it < 8; ++it) {
            int idx = t + 256 * it;
            int r = idx >> 4, f4 = idx & 15;
            int grow = row0 + r;
            float4 v = (grow < N_NODES) ? ((const float4*)x)[grow * 32 + kc * 16 + f4]
                                        : make_float4(0.f, 0.f, 0.f, 0.f);
            int k4 = f4 * 4;
            As[(k4 + 0) * 132 + r] = v.x;
            As[(k4 + 1) * 132 + r] = v.y;
            As[(k4 + 2) * 132 + r] = v.z;
            As[(k4 + 3) * 132 + r] = v.w;
        }
        __syncthreads();
#pragma unroll 4
        for (int k = 0; k < 64; ++k) {
            const float* ap = As + k * 132 + tr * 8;
            float4 a0 = *(const float4*)(ap);
            float4 a1 = *(const float4*)(ap + 4);
            float4 w = *(const float4*)(Ws + (kc * 64 + k) * C + tc * 4);
            float av[8] = {a0.x, a0.y, a0.z, a0.w, a1.x, a1.y, a1.z, a1.w};
#pragma unroll
            for (int i = 0; i < 8; ++i) {
                acc[i][0] = fmaf(av[i], w.x, acc[i][0]);
                acc[i][1] = fmaf(av[i], w.y, acc[i][1]);
                acc[i][2] = fmaf(av[i], w.z, acc[i][2]);
                acc[i][3] = fmaf(av[i], w.w, acc[i][3]);
            }
        }
    }
#pragma unroll
    for (int i = 0; i < 8; ++i) {
        int grow = row0 + tr * 8 + i;
        if (grow < N_NODES)
            ((float4*)z)[grow * 16 + tc] = make_float4(acc[i][0], acc[i][1], acc[i][2], acc[i][3]);
    }
}

// ================= CSR build =================
__global__ __launch_bounds__(256) void deg_kernel(const int* __restrict__ ei,
                                                  int* __restrict__ deg) {
    int e = blockIdx.x * 256 + threadIdx.x;
    if (e < N_EDGES) atomicAdd(&deg[ei[N_EDGES + e]], 1);
}

__global__ __launch_bounds__(256) void scan_k1(const int* __restrict__ deg,
                                               int* __restrict__ offs,
                                               int* __restrict__ partials) {
    __shared__ int s[256];
    int t = threadIdx.x;
    int i = blockIdx.x * 256 + t;
    int v = (i < N_NODES) ? deg[i] : 0;
    s[t] = v;
    for (int off = 1; off < 256; off <<= 1) {
        __syncthreads();
        int x = (t >= off) ? s[t - off] : 0;
        __syncthreads();
        s[t] += x;
    }
    __syncthreads();
    if (i < N_NODES) offs[i + 1] = s[t];
    if (t == 255) partials[blockIdx.x] = s[255];
}

__global__ __launch_bounds__(256) void scan_k2(int* __restrict__ partials) {
    __shared__ int s[256];
    int t = threadIdx.x;
    int v = (t < SCAN_BLOCKS) ? partials[t] : 0;
    s[t] = v;
    for (int off = 1; off < 256; off <<= 1) {
        __syncthreads();
        int x = (t >= off) ? s[t - off] : 0;
        __syncthreads();
        s[t] += x;
    }
    __syncthreads();
    if (t < SCAN_BLOCKS) partials[t] = s[t] - v;  // exclusive
}

__global__ __launch_bounds__(256) void scan_k3(const int* __restrict__ partials,
                                               int* __restrict__ offs,
                                               int* __restrict__ cursor) {
    int t = threadIdx.x;
    int i = blockIdx.x * 256 + t;
    if (i < N_NODES) {
        int v = offs[i + 1] + partials[blockIdx.x];
        offs[i + 1] = v;
        cursor[i + 1] = v;
    }
    if (i == 0) { offs[0] = 0; cursor[0] = 0; }
}

__global__ __launch_bounds__(256) void scatter_kernel(const int* __restrict__ ei,
                                                      int* __restrict__ cursor,
                                                      int* __restrict__ csr_src) {
    int e = blockIdx.x * 256 + threadIdx.x;
    if (e >= N_EDGES) return;
    int src = ei[e];
    int dst = ei[N_EDGES + e];
    int pos = atomicAdd(&cursor[dst], 1);
    csr_src[pos] = src;
}

// ---------------- graph start offsets from sorted batch ----------------
__global__ __launch_bounds__(256) void gstart_kernel(const int* __restrict__ batch,
                                                     int* __restrict__ goffs) {
    int n = blockIdx.x * 256 + threadIdx.x;
    if (n >= N_NODES) return;
    if (n == 0) {
        for (int g = 0; g <= batch[0]; ++g) goffs[g] = 0;
    } else {
        int bp = batch[n - 1], bc = batch[n];
        for (int g = bp + 1; g <= bc; ++g) goffs[g] = n;
    }
    if (n == N_NODES - 1) {
        for (int g = batch[n] + 1; g <= N_GRAPHS; ++g) goffs[g] = N_NODES;
    }
}

// =============================================================
// fused gather + BN-apply + GIN MLP + BN stats:
//   y[n]   = sc*(z_in[n] + sum_src z_in[src]) + (deg+1)*sh   (gather, prev-layer BN)
//   z_out  = relu(relu(y@W1+b1)@W2+b2)                       (register-tiled GEMMs)
//   stats += per-channel {sum, sumsq} of z_out               (for this layer's BN)
// ping-pong z buffers: reads all of z_in, writes own rows of z_out.
// =============================================================
__global__ __launch_bounds__(256) void mlp_gather_kernel(const int* __restrict__ csr_src,
                                                         const int* __restrict__ offs,
                                                         const float* __restrict__ z_in,
                                                         const float* __restrict__ ss,
                                                         int use_ss,
                                                         float* __restrict__ z_out,
                                                         const float* __restrict__ W1,
                                                         const float* __restrict__ b1,
                                                         const float* __restrict__ W2,
                                                         const float* __restrict__ b2,
                                                         float* __restrict__ stats) {
    __shared__ float As[64 * 132];   // [k][row] padded — reused for t1
    __shared__ float Ws[C * C];      // W1, then W2 (16 KB; 50 KB total -> 3 blocks/CU)
    int t = threadIdx.x;
    int tc = t & 15, tr = t >> 4;
    for (int i = t; i < C * C; i += 256) Ws[i] = W1[i];
    int row0 = blockIdx.x * BM;

    float4 sc = make_float4(1.f, 1.f, 1.f, 1.f);
    float4 sh = make_float4(0.f, 0.f, 0.f, 0.f);
    if (use_ss) {
        sc = ((const float4*)ss)[tc];
        sh = ((const float4*)(ss + C))[tc];
    }

    // ---- gather + BN-apply, staged transposed into As ----
    const float4* z4 = (const float4*)z_in;
    for (int it = 0; it < 8; ++it) {
        int r = tr + 16 * it;          // (t + 256*it): f4 = tc invariant, row = tr + 16*it
        int node = row0 + r;
        float4 acc = make_float4(0.f, 0.f, 0.f, 0.f);
        if (node < N_NODES) {
            int beg = offs[node], end = offs[node + 1];
            acc = z4[node * 16 + tc];  // self term (GIN eps=0)
            int e = beg;
            for (; e + 3 < end; e += 4) {  // 4-way unroll: independent loads in flight
                int s0 = csr_src[e], s1 = csr_src[e + 1], s2 = csr_src[e + 2], s3 = csr_src[e + 3];
                float4 v0 = z4[s0 * 16 + tc], v1 = z4[s1 * 16 + tc];
                float4 v2 = z4[s2 * 16 + tc], v3 = z4[s3 * 16 + tc];
                acc.x += (v0.x + v1.x) + (v2.x + v3.x);
                acc.y += (v0.y + v1.y) + (v2.y + v3.y);
                acc.z += (v0.z + v1.z) + (v2.z + v3.z);
                acc.w += (v0.w + v1.w) + (v2.w + v3.w);
            }
            for (; e < end; ++e) {
                int s = csr_src[e];
                float4 v = z4[s * 16 + tc];
                acc.x += v.x; acc.y += v.y; acc.z += v.z; acc.w += v.w;
            }
            float cnt = (float)(end - beg + 1);
            acc.x = fmaf(acc.x, sc.x, cnt * sh.x);
            acc.y = fmaf(acc.y, sc.y, cnt * sh.y);
            acc.z = fmaf(acc.z, sc.z, cnt * sh.z);
            acc.w = fmaf(acc.w, sc.w, cnt * sh.w);
        }
        int k4 = tc * 4;
        As[(k4 + 0) * 132 + r] = acc.x;
        As[(k4 + 1) * 132 + r] = acc.y;
        As[(k4 + 2) * 132 + r] = acc.z;
        As[(k4 + 3) * 132 + r] = acc.w;
    }
    __syncthreads();

    // ---- GEMM1: t1 = relu(y@W1+b1) ----
    float4 b1v = ((const float4*)b1)[tc];
    float acc[8][4];
#pragma unroll
    for (int i = 0; i < 8; ++i) { acc[i][0] = b1v.x; acc[i][1] = b1v.y; acc[i][2] = b1v.z; acc[i][3] = b1v.w; }
#pragma unroll 4
    for (int k = 0; k < 64; ++k) {
        const float* ap = As + k * 132 + tr * 8;
        float4 a0 = *(const float4*)(ap);
        float4 a1 = *(const float4*)(ap + 4);
        float4 w = *(const float4*)(Ws + k * C + tc * 4);
        float av[8] = {a0.x, a0.y, a0.z, a0.w, a1.x, a1.y, a1.z, a1.w};
#pragma unroll
        for (int i = 0; i < 8; ++i) {
            acc[i][0] = fmaf(av[i], w.x, acc[i][0]);
            acc[i][1] = fmaf(av[i], w.y, acc[i][1]);
            acc[i][2] = fmaf(av[i], w.z, acc[i][2]);
            acc[i][3] = fmaf(av[i], w.w, acc[i][3]);
        }
    }
    __syncthreads();  // all reads of As and Ws(W1) done

    // ---- restage t1^T into As; load W2 into Ws ----
#pragma unroll
    for (int i = 0; i < 8; ++i)
#pragma unroll
        for (int j = 0; j < 4; ++j)
            As[(tc * 4 + j) * 132 + tr * 8 + i] = fmaxf(acc[i][j], 0.f);
    for (int i = t; i < C * C; i += 256) Ws[i] = W2[i];
    __syncthreads();

    // ---- GEMM2: z = relu(t1@W2+b2) ----
    float4 b2v = ((const float4*)b2)[tc];
#pragma unroll
    for (int i = 0; i < 8; ++i) { acc[i][0] = b2v.x; acc[i][1] = b2v.y; acc[i][2] = b2v.z; acc[i][3] = b2v.w; }
#pragma unroll 4
    for (int k = 0; k < 64; ++k) {
        const float* ap = As + k * 132 + tr * 8;
        float4 a0 = *(const float4*)(ap);
        float4 a1 = *(const float4*)(ap + 4);
        float4 w = *(const float4*)(Ws + k * C + tc * 4);
        float av[8] = {a0.x, a0.y, a0.z, a0.w, a1.x, a1.y, a1.z, a1.w};
#pragma unroll
        for (int i = 0; i < 8; ++i) {
            acc[i][0] = fmaf(av[i], w.x, acc[i][0]);
            acc[i][1] = fmaf(av[i], w.y, acc[i][1]);
            acc[i][2] = fmaf(av[i], w.z, acc[i][2]);
            acc[i][3] = fmaf(av[i], w.w, acc[i][3]);
        }
    }

    // ---- relu, store, local BN stats ----
    float lsum[4] = {0.f, 0.f, 0.f, 0.f};
    float lsq[4] = {0.f, 0.f, 0.f, 0.f};
#pragma unroll
    for (int i = 0; i < 8; ++i) {
        int grow = row0 + tr * 8 + i;
        if (grow < N_NODES) {
            float4 o;
            o.x = fmaxf(acc[i][0], 0.f);
            o.y = fmaxf(acc[i][1], 0.f);
            o.z = fmaxf(acc[i][2], 0.f);
            o.w = fmaxf(acc[i][3], 0.f);
            ((float4*)z_out)[grow * 16 + tc] = o;
            lsum[0] += o.x; lsum[1] += o.y; lsum[2] += o.z; lsum[3] += o.w;
            lsq[0] += o.x * o.x; lsq[1] += o.y * o.y; lsq[2] += o.z * o.z; lsq[3] += o.w * o.w;
        }
    }
    __syncthreads();  // Ws reads done; reuse as reduction buffer (16x128 floats)
    float* red = Ws;
#pragma unroll
    for (int j = 0; j < 4; ++j) {
        red[tr * 128 + tc * 4 + j] = lsum[j];
        red[tr * 128 + 64 + tc * 4 + j] = lsq[j];
    }
    __syncthreads();
    if (t < 128) {
        float s = 0.f;
#pragma unroll
        for (int r = 0; r < 16; ++r) s += red[r * 128 + t];
        atomicAdd(&stats[t], s);  // stats[0..63]=sum, [64..127]=sumsq
    }
}

// ---------------- BN finalize ----------------
__global__ void bn_finalize(const float* __restrict__ stats,
                            const float* __restrict__ gamma,
                            const float* __restrict__ beta,
                            float* __restrict__ ss) {
    int c = threadIdx.x;
    if (c >= C) return;
    const float invN = 1.0f / (float)N_NODES;
    float mean = stats[c] * invN;
    float var = stats[C + c] * invN - mean * mean;
    float rstd = rsqrtf(var + BN_EPS);
    float sc = gamma[c] * rstd;
    ss[c] = sc;
    ss[C + c] = beta[c] - mean * sc;
}

// ---------------- pool: segmented reduction, one block per graph, no atomics ----------------
// g[graph] = sc * sum(z[n]) + cnt*sh   (final-layer BN fused)
__global__ __launch_bounds__(256) void pool_kernel(const float* __restrict__ z,
                                                   const float* __restrict__ ss,
                                                   const int* __restrict__ goffs,
                                                   float* __restrict__ g) {
    __shared__ float4 red[256];  // 4 KB
    int t = threadIdx.x;
    int tc = t & 15, tr = t >> 4;
    int gr = blockIdx.x;
    int beg = goffs[gr], end = goffs[gr + 1];
    const float4* z4 = (const float4*)z;
    float4 acc = make_float4(0.f, 0.f, 0.f, 0.f);
    for (int n = beg + tr; n < end; n += 16) {
        float4 v = z4[n * 16 + tc];
        acc.x += v.x; acc.y += v.y; acc.z += v.z; acc.w += v.w;
    }
    red[tr * 16 + tc] = acc;
    for (int s = 8; s > 0; s >>= 1) {
        __syncthreads();
        if (tr < s) {
            float4 o = red[(tr + s) * 16 + tc];
            float4 m = red[tr * 16 + tc];
            m.x += o.x; m.y += o.y; m.z += o.z; m.w += o.w;
            red[tr * 16 + tc] = m;
        }
    }
    __syncthreads();
    if (tr == 0) {
        float4 sum = red[tc];
        float4 sc = ((const float4*)ss)[tc];
        float4 sh = ((const float4*)(ss + C))[tc];
        float cnt = (float)(end - beg);
        float4 o;
        o.x = fmaf(sum.x, sc.x, cnt * sh.x);
        o.y = fmaf(sum.y, sc.y, cnt * sh.y);
        o.z = fmaf(sum.z, sc.z, cnt * sh.z);
        o.w = fmaf(sum.w, sc.w, cnt * sh.w);
        ((float4*)g)[gr * 16 + tc] = o;
    }
}

// ---------------- head ----------------
__global__ __launch_bounds__(256) void head_kernel(const float* __restrict__ g,
                                                   const float* __restrict__ fc1W,
                                                   const float* __restrict__ fc1b,
                                                   const float* __restrict__ fc2W,
                                                   const float* __restrict__ fc2b,
                                                   float* __restrict__ out) {
    __shared__ float W1s[C * C];
    __shared__ float W2s[C * 16];
    __shared__ float gs[4][C], t1s[4][C];
    int t = threadIdx.x;
    for (int i = t; i < C * C; i += 256) W1s[i] = fc1W[i];
    for (int i = t; i < C * 16; i += 256) W2s[i] = fc2W[i];
    int ch = t & 63, rr = t >> 6;
    int g0 = blockIdx.x * 4;
    gs[rr][ch] = g[(g0 + rr) * C + ch];
    __syncthreads();
    float a1 = fc1b[ch];
#pragma unroll 8
    for (int k = 0; k < C; ++k) a1 = fmaf(gs[rr][k], W1s[k * C + ch], a1);
    t1s[rr][ch] = fmaxf(a1, 0.f);
    __syncthreads();
    if (t < 64) {
        int o = t & 15, r2 = t >> 4;
        float a2 = fc2b[o];
#pragma unroll 8
        for (int k = 0; k < C; ++k) a2 = fmaf(t1s[r2][k], W2s[k * 16 + o], a2);
        out[(g0 + r2) * 16 + o] = a2;
    }
}

extern "C" void kernel_launch(void* const* d_in, const int* in_sizes, int n_in,
                              void* d_out, int out_size, void* d_ws, size_t ws_size,
                              hipStream_t stream) {
    const float* x    = (const float*)d_in[0];
    const int*   ei   = (const int*)d_in[1];
    const int*   batch= (const int*)d_in[2];
    const float* encW = (const float*)d_in[3];
    const float* encb = (const float*)d_in[4];
    const float* cW1  = (const float*)d_in[5];
    const float* cb1  = (const float*)d_in[6];
    const float* cW2  = (const float*)d_in[7];
    const float* cb2  = (const float*)d_in[8];
    const float* gam  = (const float*)d_in[9];
    const float* bet  = (const float*)d_in[10];
    const float* f1W  = (const float*)d_in[11];
    const float* f1b  = (const float*)d_in[12];
    const float* f2W  = (const float*)d_in[13];
    const float* f2b  = (const float*)d_in[14];
    float* out = (float*)d_out;

    char* ws = (char*)d_ws;
    float* zA      = (float*)(ws);                    // 12.8 MB
    float* zB      = (float*)(ws + 12800000);         // 12.8 MB
    int*   csr     = (int*)  (ws + 25600000);         // 3.2 MB
    int*   offs    = (int*)  (ws + 28800000);         // 200,064 B
    int*   deg     = (int*)  (ws + 29000064);         // 200,000 B
    int*   cursor  = (int*)  (ws + 29200064);         // 200,064 B
    int*   partials= (int*)  (ws + 29400128);         // 1 KB
    float* stats   = (float*)(ws + 29401152);         // 5*128 floats = 2560 B
    float* ssb     = (float*)(ws + 29403712);         // 5*128 floats = 2560 B
    int*   goffs   = (int*)  (ws + 29406272);         // 513 ints
    float* gpool   = (float*)(ws + 29408384);         // 128 KB

    // --- CSR build + graph offsets (once per call) ---
    hipMemsetAsync(deg, 0, (size_t)N_NODES * sizeof(int), stream);
    hipMemsetAsync(stats, 0, 5 * 2 * C * sizeof(float), stream);
    deg_kernel<<<(N_EDGES + 255) / 256, 256, 0, stream>>>(ei, deg);
    scan_k1<<<SCAN_BLOCKS, 256, 0, stream>>>(deg, offs, partials);
    scan_k2<<<1, 256, 0, stream>>>(partials);
    scan_k3<<<SCAN_BLOCKS, 256, 0, stream>>>(partials, offs, cursor);
    scatter_kernel<<<(N_EDGES + 255) / 256, 256, 0, stream>>>(ei, cursor, csr);
    gstart_kernel<<<SCAN_BLOCKS, 256, 0, stream>>>(batch, goffs);

    enc_kernel<<<(N_NODES + BM - 1) / BM, 256, 0, stream>>>(x, encW, encb, zA);

    float* zin = zA;
    float* zout = zB;
    for (int l = 0; l < N_LAYERS; ++l) {
        mlp_gather_kernel<<<(N_NODES + BM - 1) / BM, 256, 0, stream>>>(
            csr, offs, zin, ssb + (size_t)(l - 1) * 2 * C, l > 0 ? 1 : 0, zout,
            cW1 + (size_t)l * C * C, cb1 + (size_t)l * C,
            cW2 + (size_t)l * C * C, cb2 + (size_t)l * C,
            stats + (size_t)l * 2 * C);
        bn_finalize<<<1, 64, 0, stream>>>(stats + (size_t)l * 2 * C,
                                          gam + (size_t)l * C, bet + (size_t)l * C,
                                          ssb + (size_t)l * 2 * C);
        float* tmp = zin; zin = zout; zout = tmp;
    }

    // zin now holds layer-5 pre-BN output; pool applies final BN
    pool_kernel<<<N_GRAPHS, 256, 0, stream>>>(zin, ssb + (size_t)(N_LAYERS - 1) * 2 * C, goffs, gpool);
    head_kernel<<<N_GRAPHS / 4, 256, 0, stream>>>(gpool, f1W, f1b, f2W, f2b, out);
}

// Round 5
// 489.438 us; speedup vs baseline: 8.3928x; 1.2035x over previous
//
#include <hip/hip_runtime.h>

#define N_NODES 50000
#define N_EDGES 800000
#define NODE_DIM 128
#define C 64
#define N_GRAPHS 512
#define N_LAYERS 5
#define BN_EPS 1e-5f

#define SCAN_BLOCKS 196  // ceil(50000/256)

typedef unsigned int u32;

// bf16 helpers: z intermediates stored as bf16 (2 ch per u32 word)
__device__ inline float bfhi(u32 v) {  // high 16 bits as bf16
    u32 x = v & 0xFFFF0000u;
    float f; __builtin_memcpy(&f, &x, 4); return f;
}
__device__ inline float bflo(u32 v) {  // low 16 bits as bf16
    u32 x = v << 16;
    float f; __builtin_memcpy(&f, &x, 4); return f;
}
__device__ inline u32 f2bf(float f) {  // RTNE
    u32 x; __builtin_memcpy(&x, &f, 4);
    return (x + 0x7FFFu + ((x >> 16) & 1u)) >> 16;
}
__device__ inline u32 pack2(float a, float b) { return f2bf(a) | (f2bf(b) << 16); }

// =============================================================
// encoder: z = x @ enc_W + enc_b   [50000,128]x[128,64], z stored bf16
// register-tiled: 256 thr = 16 tc x 16 tr, TM=8 rows, TN=4 cols, BM=128
// =============================================================
__global__ __launch_bounds__(256) void enc_kernel(const float* __restrict__ x,
                                                  const float* __restrict__ W,
                                                  const float* __restrict__ b,
                                                  u32* __restrict__ z) {
    __shared__ float As[64 * 132];        // [k][row], row-dim padded
    __shared__ float Ws[NODE_DIM * C];    // 32 KB, full K
    int t = threadIdx.x;
    int tc = t & 15, tr = t >> 4;
    for (int i = t; i < NODE_DIM * C; i += 256) Ws[i] = W[i];
    int row0 = blockIdx.x * 128;
    float4 bv = ((const float4*)b)[tc];
    float acc[8][4];
#pragma unroll
    for (int i = 0; i < 8; ++i) { acc[i][0] = bv.x; acc[i][1] = bv.y; acc[i][2] = bv.z; acc[i][3] = bv.w; }

    for (int kc = 0; kc < 2; ++kc) {
        __syncthreads();
        for (int it = 0; it < 8; ++it) {
            int idx = t + 256 * it;
            int r = idx >> 4, f4 = idx & 15;
            int grow = row0 + r;
            float4 v = (grow < N_NODES) ? ((const float4*)x)[grow * 32 + kc * 16 + f4]
                                        : make_float4(0.f, 0.f, 0.f, 0.f);
            int k4 = f4 * 4;
            As[(k4 + 0) * 132 + r] = v.x;
            As[(k4 + 1) * 132 + r] = v.y;
            As[(k4 + 2) * 132 + r] = v.z;
            As[(k4 + 3) * 132 + r] = v.w;
        }
        __syncthreads();
#pragma unroll 4
        for (int k = 0; k < 64; ++k) {
            const float* ap = As + k * 132 + tr * 8;
            float4 a0 = *(const float4*)(ap);
            float4 a1 = *(const float4*)(ap + 4);
            float4 w = *(const float4*)(Ws + (kc * 64 + k) * C + tc * 4);
            float av[8] = {a0.x, a0.y, a0.z, a0.w, a1.x, a1.y, a1.z, a1.w};
#pragma unroll
            for (int i = 0; i < 8; ++i) {
                acc[i][0] = fmaf(av[i], w.x, acc[i][0]);
                acc[i][1] = fmaf(av[i], w.y, acc[i][1]);
                acc[i][2] = fmaf(av[i], w.z, acc[i][2]);
                acc[i][3] = fmaf(av[i], w.w, acc[i][3]);
            }
        }
    }
#pragma unroll
    for (int i = 0; i < 8; ++i) {
        int grow = row0 + tr * 8 + i;
        if (grow < N_NODES) {
            uint2 o;
            o.x = pack2(acc[i][0], acc[i][1]);
            o.y = pack2(acc[i][2], acc[i][3]);
            ((uint2*)z)[grow * 16 + tc] = o;
        }
    }
}

// ================= CSR build =================
__global__ __launch_bounds__(256) void deg_kernel(const int* __restrict__ ei,
                                                  int* __restrict__ deg) {
    int e = blockIdx.x * 256 + threadIdx.x;
    if (e < N_EDGES) atomicAdd(&deg[ei[N_EDGES + e]], 1);
}

__global__ __launch_bounds__(256) void scan_k1(const int* __restrict__ deg,
                                               int* __restrict__ offs,
                                               int* __restrict__ partials) {
    __shared__ int s[256];
    int t = threadIdx.x;
    int i = blockIdx.x * 256 + t;
    int v = (i < N_NODES) ? deg[i] : 0;
    s[t] = v;
    for (int off = 1; off < 256; off <<= 1) {
        __syncthreads();
        int x = (t >= off) ? s[t - off] : 0;
        __syncthreads();
        s[t] += x;
    }
    __syncthreads();
    if (i < N_NODES) offs[i + 1] = s[t];
    if (t == 255) partials[blockIdx.x] = s[255];
}

__global__ __launch_bounds__(256) void scan_k2(int* __restrict__ partials) {
    __shared__ int s[256];
    int t = threadIdx.x;
    int v = (t < SCAN_BLOCKS) ? partials[t] : 0;
    s[t] = v;
    for (int off = 1; off < 256; off <<= 1) {
        __syncthreads();
        int x = (t >= off) ? s[t - off] : 0;
        __syncthreads();
        s[t] += x;
    }
    __syncthreads();
    if (t < SCAN_BLOCKS) partials[t] = s[t] - v;  // exclusive
}

__global__ __launch_bounds__(256) void scan_k3(const int* __restrict__ partials,
                                               int* __restrict__ offs,
                                               int* __restrict__ cursor) {
    int t = threadIdx.x;
    int i = blockIdx.x * 256 + t;
    if (i < N_NODES) {
        int v = offs[i + 1] + partials[blockIdx.x];
        offs[i + 1] = v;
        cursor[i + 1] = v;
    }
    if (i == 0) { offs[0] = 0; cursor[0] = 0; }
}

__global__ __launch_bounds__(256) void scatter_kernel(const int* __restrict__ ei,
                                                      int* __restrict__ cursor,
                                                      int* __restrict__ csr_src) {
    int e = blockIdx.x * 256 + threadIdx.x;
    if (e >= N_EDGES) return;
    int src = ei[e];
    int dst = ei[N_EDGES + e];
    int pos = atomicAdd(&cursor[dst], 1);
    csr_src[pos] = src;
}

// ---------------- graph start offsets from sorted batch ----------------
__global__ __launch_bounds__(256) void gstart_kernel(const int* __restrict__ batch,
                                                     int* __restrict__ goffs) {
    int n = blockIdx.x * 256 + threadIdx.x;
    if (n >= N_NODES) return;
    if (n == 0) {
        for (int g = 0; g <= batch[0]; ++g) goffs[g] = 0;
    } else {
        int bp = batch[n - 1], bc = batch[n];
        for (int g = bp + 1; g <= bc; ++g) goffs[g] = n;
    }
    if (n == N_NODES - 1) {
        for (int g = batch[n] + 1; g <= N_GRAPHS; ++g) goffs[g] = N_NODES;
    }
}

// =============================================================
// fused gather(bf16) + BN-apply + GIN MLP(fp32) + BN stats, BM=64
//   y[n]  = sc*(z_in[n] + sum_src z_in[src]) + (deg+1)*sh
//   z_out = bf16(relu(relu(y@W1+b1)@W2+b2))
// 256 thr: tc=t&15 (4-ch group), tr=t>>4 (row group). 782 blocks, 34 KB LDS
// -> 4 blocks/CU, whole grid co-resident (latency hiding for the gather).
// =============================================================
__global__ __launch_bounds__(256) void mlp_gather_kernel(const int* __restrict__ csr_src,
                                                         const int* __restrict__ offs,
                                                         const u32* __restrict__ z_in,
                                                         const float* __restrict__ ss,
                                                         int use_ss,
                                                         u32* __restrict__ z_out,
                                                         const float* __restrict__ W1,
                                                         const float* __restrict__ b1,
                                                         const float* __restrict__ W2,
                                                         const float* __restrict__ b2,
                                                         float* __restrict__ stats) {
    __shared__ float As[64 * 68];    // [k][row], 17.4 KB — reused for t1
    __shared__ float Ws[C * C];      // 16 KB: W1, then W2, then stats-reduce
    int t = threadIdx.x;
    int tc = t & 15, tr = t >> 4;
    for (int i = t; i < C * C; i += 256) Ws[i] = W1[i];
    int row0 = blockIdx.x * 64;

    float4 sc = make_float4(1.f, 1.f, 1.f, 1.f);
    float4 sh = make_float4(0.f, 0.f, 0.f, 0.f);
    if (use_ss) {
        sc = ((const float4*)ss)[tc];
        sh = ((const float4*)(ss + C))[tc];
    }

    // ---- gather + BN-apply, staged transposed into As ----
    const uint2* z2 = (const uint2*)z_in;   // 8 B = 4 bf16 channels
    for (int it = 0; it < 4; ++it) {
        int r = tr + 16 * it;               // 0..63
        int node = row0 + r;
        float4 acc = make_float4(0.f, 0.f, 0.f, 0.f);
        if (node < N_NODES) {
            uint2 sv = z2[node * 16 + tc];  // self term (GIN eps=0)
            acc.x = bflo(sv.x); acc.y = bfhi(sv.x); acc.z = bflo(sv.y); acc.w = bfhi(sv.y);
            int beg = offs[node], end = offs[node + 1];
            int e = beg;
            for (; e + 3 < end; e += 4) {   // 4 independent line-loads in flight
                int s0 = csr_src[e], s1 = csr_src[e + 1], s2 = csr_src[e + 2], s3 = csr_src[e + 3];
                uint2 v0 = z2[s0 * 16 + tc], v1 = z2[s1 * 16 + tc];
                uint2 v2 = z2[s2 * 16 + tc], v3 = z2[s3 * 16 + tc];
                acc.x += (bflo(v0.x) + bflo(v1.x)) + (bflo(v2.x) + bflo(v3.x));
                acc.y += (bfhi(v0.x) + bfhi(v1.x)) + (bfhi(v2.x) + bfhi(v3.x));
                acc.z += (bflo(v0.y) + bflo(v1.y)) + (bflo(v2.y) + bflo(v3.y));
                acc.w += (bfhi(v0.y) + bfhi(v1.y)) + (bfhi(v2.y) + bfhi(v3.y));
            }
            for (; e < end; ++e) {
                uint2 v = z2[csr_src[e] * 16 + tc];
                acc.x += bflo(v.x); acc.y += bfhi(v.x); acc.z += bflo(v.y); acc.w += bfhi(v.y);
            }
            float cnt = (float)(end - beg + 1);
            acc.x = fmaf(acc.x, sc.x, cnt * sh.x);
            acc.y = fmaf(acc.y, sc.y, cnt * sh.y);
            acc.z = fmaf(acc.z, sc.z, cnt * sh.z);
            acc.w = fmaf(acc.w, sc.w, cnt * sh.w);
        }
        int k4 = tc * 4;
        As[(k4 + 0) * 68 + r] = acc.x;
        As[(k4 + 1) * 68 + r] = acc.y;
        As[(k4 + 2) * 68 + r] = acc.z;
        As[(k4 + 3) * 68 + r] = acc.w;
    }
    __syncthreads();

    // ---- GEMM1: t1 = relu(y@W1+b1), TM=4 x TN=4 ----
    float4 b1v = ((const float4*)b1)[tc];
    float a[4][4];
#pragma unroll
    for (int i = 0; i < 4; ++i) { a[i][0] = b1v.x; a[i][1] = b1v.y; a[i][2] = b1v.z; a[i][3] = b1v.w; }
#pragma unroll 4
    for (int k = 0; k < 64; ++k) {
        float4 av = *(const float4*)(As + k * 68 + tr * 4);
        float4 w = *(const float4*)(Ws + k * C + tc * 4);
        float avv[4] = {av.x, av.y, av.z, av.w};
#pragma unroll
        for (int i = 0; i < 4; ++i) {
            a[i][0] = fmaf(avv[i], w.x, a[i][0]);
            a[i][1] = fmaf(avv[i], w.y, a[i][1]);
            a[i][2] = fmaf(avv[i], w.z, a[i][2]);
            a[i][3] = fmaf(avv[i], w.w, a[i][3]);
        }
    }
    __syncthreads();  // As + Ws(W1) reads done

    // ---- restage t1^T into As; load W2 ----
#pragma unroll
    for (int i = 0; i < 4; ++i)
#pragma unroll
        for (int j = 0; j < 4; ++j)
            As[(tc * 4 + j) * 68 + tr * 4 + i] = fmaxf(a[i][j], 0.f);
    for (int i = t; i < C * C; i += 256) Ws[i] = W2[i];
    __syncthreads();

    // ---- GEMM2: z = relu(t1@W2+b2) ----
    float4 b2v = ((const float4*)b2)[tc];
#pragma unroll
    for (int i = 0; i < 4; ++i) { a[i][0] = b2v.x; a[i][1] = b2v.y; a[i][2] = b2v.z; a[i][3] = b2v.w; }
#pragma unroll 4
    for (int k = 0; k < 64; ++k) {
        float4 av = *(const float4*)(As + k * 68 + tr * 4);
        float4 w = *(const float4*)(Ws + k * C + tc * 4);
        float avv[4] = {av.x, av.y, av.z, av.w};
#pragma unroll
        for (int i = 0; i < 4; ++i) {
            a[i][0] = fmaf(avv[i], w.x, a[i][0]);
            a[i][1] = fmaf(avv[i], w.y, a[i][1]);
            a[i][2] = fmaf(avv[i], w.z, a[i][2]);
            a[i][3] = fmaf(avv[i], w.w, a[i][3]);
        }
    }

    // ---- relu, bf16 store, local BN stats (fp32, pre-rounding) ----
    float lsum[4] = {0.f, 0.f, 0.f, 0.f};
    float lsq[4] = {0.f, 0.f, 0.f, 0.f};
#pragma unroll
    for (int i = 0; i < 4; ++i) {
        int grow = row0 + tr * 4 + i;
        if (grow < N_NODES) {
            float o0 = fmaxf(a[i][0], 0.f), o1 = fmaxf(a[i][1], 0.f);
            float o2 = fmaxf(a[i][2], 0.f), o3 = fmaxf(a[i][3], 0.f);
            uint2 o;
            o.x = pack2(o0, o1);
            o.y = pack2(o2, o3);
            ((uint2*)z_out)[grow * 16 + tc] = o;
            lsum[0] += o0; lsum[1] += o1; lsum[2] += o2; lsum[3] += o3;
            lsq[0] += o0 * o0; lsq[1] += o1 * o1; lsq[2] += o2 * o2; lsq[3] += o3 * o3;
        }
    }
    __syncthreads();  // Ws(W2) reads done; reuse as reduction buffer 16x128
    float* red = Ws;
#pragma unroll
    for (int j = 0; j < 4; ++j) {
        red[tr * 128 + tc * 4 + j] = lsum[j];
        red[tr * 128 + 64 + tc * 4 + j] = lsq[j];
    }
    __syncthreads();
    if (t < 128) {
        float s = 0.f;
#pragma unroll
        for (int r = 0; r < 16; ++r) s += red[r * 128 + t];
        atomicAdd(&stats[t], s);  // [0..63]=sum, [64..127]=sumsq
    }
}

// ---------------- BN finalize ----------------
__global__ void bn_finalize(const float* __restrict__ stats,
                            const float* __restrict__ gamma,
                            const float* __restrict__ beta,
                            float* __restrict__ ss) {
    int c = threadIdx.x;
    if (c >= C) return;
    const float invN = 1.0f / (float)N_NODES;
    float mean = stats[c] * invN;
    float var = stats[C + c] * invN - mean * mean;
    float rstd = rsqrtf(var + BN_EPS);
    float sc = gamma[c] * rstd;
    ss[c] = sc;
    ss[C + c] = beta[c] - mean * sc;
}

// ---------------- pool: segmented reduction over sorted batch, no atomics ----------------
// g[graph] = sc * sum(z[n]) + cnt*sh   (final-layer BN fused), z is bf16
__global__ __launch_bounds__(256) void pool_kernel(const u32* __restrict__ z,
                                                   const float* __restrict__ ss,
                                                   const int* __restrict__ goffs,
                                                   float* __restrict__ g) {
    __shared__ float4 red[256];
    int t = threadIdx.x;
    int tc = t & 15, tr = t >> 4;
    int gr = blockIdx.x;
    int beg = goffs[gr], end = goffs[gr + 1];
    const uint2* z2 = (const uint2*)z;
    float4 acc = make_float4(0.f, 0.f, 0.f, 0.f);
    for (int n = beg + tr; n < end; n += 16) {
        uint2 v = z2[n * 16 + tc];
        acc.x += bflo(v.x); acc.y += bfhi(v.x); acc.z += bflo(v.y); acc.w += bfhi(v.y);
    }
    red[tr * 16 + tc] = acc;
    for (int s = 8; s > 0; s >>= 1) {
        __syncthreads();
        if (tr < s) {
            float4 o = red[(tr + s) * 16 + tc];
            float4 m = red[tr * 16 + tc];
            m.x += o.x; m.y += o.y; m.z += o.z; m.w += o.w;
            red[tr * 16 + tc] = m;
        }
    }
    __syncthreads();
    if (tr == 0) {
        float4 sum = red[tc];
        float4 sc = ((const float4*)ss)[tc];
        float4 sh = ((const float4*)(ss + C))[tc];
        float cnt = (float)(end - beg);
        float4 o;
        o.x = fmaf(sum.x, sc.x, cnt * sh.x);
        o.y = fmaf(sum.y, sc.y, cnt * sh.y);
        o.z = fmaf(sum.z, sc.z, cnt * sh.z);
        o.w = fmaf(sum.w, sc.w, cnt * sh.w);
        ((float4*)g)[gr * 16 + tc] = o;
    }
}

// ---------------- head ----------------
__global__ __launch_bounds__(256) void head_kernel(const float* __restrict__ g,
                                                   const float* __restrict__ fc1W,
                                                   const float* __restrict__ fc1b,
                                                   const float* __restrict__ fc2W,
                                                   const float* __restrict__ fc2b,
                                                   float* __restrict__ out) {
    __shared__ float W1s[C * C];
    __shared__ float W2s[C * 16];
    __shared__ float gs[4][C], t1s[4][C];
    int t = threadIdx.x;
    for (int i = t; i < C * C; i += 256) W1s[i] = fc1W[i];
    for (int i = t; i < C * 16; i += 256) W2s[i] = fc2W[i];
    int ch = t & 63, rr = t >> 6;
    int g0 = blockIdx.x * 4;
    gs[rr][ch] = g[(g0 + rr) * C + ch];
    __syncthreads();
    float a1 = fc1b[ch];
#pragma unroll 8
    for (int k = 0; k < C; ++k) a1 = fmaf(gs[rr][k], W1s[k * C + ch], a1);
    t1s[rr][ch] = fmaxf(a1, 0.f);
    __syncthreads();
    if (t < 64) {
        int o = t & 15, r2 = t >> 4;
        float a2 = fc2b[o];
#pragma unroll 8
        for (int k = 0; k < C; ++k) a2 = fmaf(t1s[r2][k], W2s[k * 16 + o], a2);
        out[(g0 + r2) * 16 + o] = a2;
    }
}

extern "C" void kernel_launch(void* const* d_in, const int* in_sizes, int n_in,
                              void* d_out, int out_size, void* d_ws, size_t ws_size,
                              hipStream_t stream) {
    const float* x    = (const float*)d_in[0];
    const int*   ei   = (const int*)d_in[1];
    const int*   batch= (const int*)d_in[2];
    const float* encW = (const float*)d_in[3];
    const float* encb = (const float*)d_in[4];
    const float* cW1  = (const float*)d_in[5];
    const float* cb1  = (const float*)d_in[6];
    const float* cW2  = (const float*)d_in[7];
    const float* cb2  = (const float*)d_in[8];
    const float* gam  = (const float*)d_in[9];
    const float* bet  = (const float*)d_in[10];
    const float* f1W  = (const float*)d_in[11];
    const float* f1b  = (const float*)d_in[12];
    const float* f2W  = (const float*)d_in[13];
    const float* f2b  = (const float*)d_in[14];
    float* out = (float*)d_out;

    char* ws = (char*)d_ws;
    u32*   zA      = (u32*)  (ws);                    // bf16: 6.4 MB
    u32*   zB      = (u32*)  (ws + 6400000);          // bf16: 6.4 MB
    int*   csr     = (int*)  (ws + 12800000);         // 3.2 MB
    int*   offs    = (int*)  (ws + 16000000);         // 200,064 B
    int*   deg     = (int*)  (ws + 16200064);         // 200,000 B
    int*   cursor  = (int*)  (ws + 16400064);         // 200,064 B
    int*   partials= (int*)  (ws + 16600128);         // 1 KB
    float* stats   = (float*)(ws + 16601152);         // 5*128 floats
    float* ssb     = (float*)(ws + 16603712);         // 5*128 floats
    int*   goffs   = (int*)  (ws + 16606272);         // 513 ints
    float* gpool   = (float*)(ws + 16608384);         // 128 KB

    // --- CSR build + graph offsets (once per call) ---
    hipMemsetAsync(deg, 0, (size_t)N_NODES * sizeof(int), stream);
    hipMemsetAsync(stats, 0, 5 * 2 * C * sizeof(float), stream);
    deg_kernel<<<(N_EDGES + 255) / 256, 256, 0, stream>>>(ei, deg);
    scan_k1<<<SCAN_BLOCKS, 256, 0, stream>>>(deg, offs, partials);
    scan_k2<<<1, 256, 0, stream>>>(partials);
    scan_k3<<<SCAN_BLOCKS, 256, 0, stream>>>(partials, offs, cursor);
    scatter_kernel<<<(N_EDGES + 255) / 256, 256, 0, stream>>>(ei, cursor, csr);
    gstart_kernel<<<SCAN_BLOCKS, 256, 0, stream>>>(batch, goffs);

    enc_kernel<<<(N_NODES + 127) / 128, 256, 0, stream>>>(x, encW, encb, zA);

    u32* zin = zA;
    u32* zout = zB;
    for (int l = 0; l < N_LAYERS; ++l) {
        const float* ss_prev = (l > 0) ? (ssb + (size_t)(l - 1) * 2 * C) : ssb;
        mlp_gather_kernel<<<(N_NODES + 63) / 64, 256, 0, stream>>>(
            csr, offs, zin, ss_prev, l > 0 ? 1 : 0, zout,
            cW1 + (size_t)l * C * C, cb1 + (size_t)l * C,
            cW2 + (size_t)l * C * C, cb2 + (size_t)l * C,
            stats + (size_t)l * 2 * C);
        bn_finalize<<<1, 64, 0, stream>>>(stats + (size_t)l * 2 * C,
                                          gam + (size_t)l * C, bet + (size_t)l * C,
                                          ssb + (size_t)l * 2 * C);
        u32* tmp = zin; zin = zout; zout = tmp;
    }

    // zin holds layer-5 pre-BN output (bf16); pool applies final BN
    pool_kernel<<<N_GRAPHS, 256, 0, stream>>>(zin, ssb + (size_t)(N_LAYERS - 1) * 2 * C, goffs, gpool);
    head_kernel<<<N_GRAPHS / 4, 256, 0, stream>>>(gpool, f1W, f1b, f2W, f2b, out);
}

// Round 6
// 432.982 us; speedup vs baseline: 9.4872x; 1.1304x over previous
//
#include <hip/hip_runtime.h>
#include <hip/hip_fp16.h>

#define N_NODES 50000
#define N_EDGES 800000
#define NODE_DIM 128
#define C 64
#define N_GRAPHS 512
#define N_LAYERS 5
#define BN_EPS 1e-5f

#define SCAN_BLOCKS 196   // ceil(50000/256)
#define NBUCK 196         // buckets of 256 nodes: bucket = dst >> 8
#define ECHUNK 4096       // edges per block in CSR-build passes

typedef unsigned int u32;

// fp16 helpers: z intermediates stored as fp16 (2 ch per u32 word)
__device__ inline float2 h2f(u32 v) {
    __half2 h; __builtin_memcpy(&h, &v, 4);
    return __half22float2(h);
}
__device__ inline u32 f2h2(float a, float b) {
    __half2 h = __floats2half2_rn(a, b);
    u32 v; __builtin_memcpy(&v, &h, 4);
    return v;
}

// =============================================================
// encoder: z = x @ enc_W + enc_b   [50000,128]x[128,64], z stored fp16
// =============================================================
__global__ __launch_bounds__(256) void enc_kernel(const float* __restrict__ x,
                                                  const float* __restrict__ W,
                                                  const float* __restrict__ b,
                                                  u32* __restrict__ z) {
    __shared__ float As[64 * 132];        // [k][row], row-dim padded
    __shared__ float Ws[NODE_DIM * C];    // 32 KB, full K
    int t = threadIdx.x;
    int tc = t & 15, tr = t >> 4;
    for (int i = t; i < NODE_DIM * C; i += 256) Ws[i] = W[i];
    int row0 = blockIdx.x * 128;
    float4 bv = ((const float4*)b)[tc];
    float acc[8][4];
#pragma unroll
    for (int i = 0; i < 8; ++i) { acc[i][0] = bv.x; acc[i][1] = bv.y; acc[i][2] = bv.z; acc[i][3] = bv.w; }

    for (int kc = 0; kc < 2; ++kc) {
        __syncthreads();
        for (int it = 0; it < 8; ++it) {
            int idx = t + 256 * it;
            int r = idx >> 4, f4 = idx & 15;
            int grow = row0 + r;
            float4 v = (grow < N_NODES) ? ((const float4*)x)[grow * 32 + kc * 16 + f4]
                                        : make_float4(0.f, 0.f, 0.f, 0.f);
            int k4 = f4 * 4;
            As[(k4 + 0) * 132 + r] = v.x;
            As[(k4 + 1) * 132 + r] = v.y;
            As[(k4 + 2) * 132 + r] = v.z;
            As[(k4 + 3) * 132 + r] = v.w;
        }
        __syncthreads();
#pragma unroll 4
        for (int k = 0; k < 64; ++k) {
            const float* ap = As + k * 132 + tr * 8;
            float4 a0 = *(const float4*)(ap);
            float4 a1 = *(const float4*)(ap + 4);
            float4 w = *(const float4*)(Ws + (kc * 64 + k) * C + tc * 4);
            float av[8] = {a0.x, a0.y, a0.z, a0.w, a1.x, a1.y, a1.z, a1.w};
#pragma unroll
            for (int i = 0; i < 8; ++i) {
                acc[i][0] = fmaf(av[i], w.x, acc[i][0]);
                acc[i][1] = fmaf(av[i], w.y, acc[i][1]);
                acc[i][2] = fmaf(av[i], w.z, acc[i][2]);
                acc[i][3] = fmaf(av[i], w.w, acc[i][3]);
            }
        }
    }
#pragma unroll
    for (int i = 0; i < 8; ++i) {
        int grow = row0 + tr * 8 + i;
        if (grow < N_NODES) {
            uint2 o;
            o.x = f2h2(acc[i][0], acc[i][1]);
            o.y = f2h2(acc[i][2], acc[i][3]);
            ((uint2*)z)[grow * 16 + tc] = o;
        }
    }
}

// ================= bucketed CSR build =================
// A1: bucket histogram (bucket = dst >> 8)
__global__ __launch_bounds__(256) void csr_hist(const int* __restrict__ ei,
                                                int* __restrict__ bcount) {
    __shared__ int lhist[NBUCK];
    int t = threadIdx.x;
    if (t < NBUCK) lhist[t] = 0;
    __syncthreads();
    int e0 = blockIdx.x * ECHUNK;
    int e1 = min(e0 + ECHUNK, N_EDGES);
    for (int e = e0 + t; e < e1; e += 256)
        atomicAdd(&lhist[ei[N_EDGES + e] >> 8], 1);
    __syncthreads();
    if (t < NBUCK && lhist[t] > 0) atomicAdd(&bcount[t], lhist[t]);
}

// scan over buckets: bbase (exclusive), bcursor seed, offs[N]
__global__ __launch_bounds__(256) void csr_bscan(const int* __restrict__ bcount,
                                                 int* __restrict__ bbase,
                                                 int* __restrict__ bcursor,
                                                 int* __restrict__ offs) {
    __shared__ int s[256];
    int t = threadIdx.x;
    int v = (t < NBUCK) ? bcount[t] : 0;
    s[t] = v;
    for (int off = 1; off < 256; off <<= 1) {
        __syncthreads();
        int x = (t >= off) ? s[t - off] : 0;
        __syncthreads();
        s[t] += x;
    }
    __syncthreads();
    if (t < NBUCK) {
        bbase[t + 1] = s[t];
        bcursor[t] = s[t] - v;   // exclusive base = cursor seed
    }
    if (t == 0) { bbase[0] = 0; offs[N_NODES] = N_EDGES; }
}

// A2: stage entries bucket-major with per-(block,bucket) range reservation.
// entry = src | (dstLow8 << 16)   (src < 65536)
__global__ __launch_bounds__(256) void csr_stage(const int* __restrict__ ei,
                                                 int* __restrict__ bcursor,
                                                 u32* __restrict__ staged) {
    __shared__ int lhist[NBUCK];
    __shared__ int lbase[NBUCK];
    __shared__ int lcur[NBUCK];
    int t = threadIdx.x;
    if (t < NBUCK) lhist[t] = 0;
    __syncthreads();
    int e0 = blockIdx.x * ECHUNK;
    int e1 = min(e0 + ECHUNK, N_EDGES);
    for (int e = e0 + t; e < e1; e += 256)
        atomicAdd(&lhist[ei[N_EDGES + e] >> 8], 1);
    __syncthreads();
    if (t < NBUCK) {
        int c = lhist[t];
        lbase[t] = (c > 0) ? atomicAdd(&bcursor[t], c) : 0;  // reserve contiguous run
        lcur[t] = 0;
    }
    __syncthreads();
    for (int e = e0 + t; e < e1; e += 256) {
        int src = ei[e];
        int dst = ei[N_EDGES + e];
        int bk = dst >> 8;
        int r = atomicAdd(&lcur[bk], 1);
        staged[lbase[bk] + r] = (u32)src | ((u32)(dst & 255) << 16);
    }
}

// B: per-bucket counting sort -> csr segment + per-node offs (block-private writes)
__global__ __launch_bounds__(256) void csr_finalize(const u32* __restrict__ staged,
                                                    const int* __restrict__ bbase,
                                                    int* __restrict__ csr,
                                                    int* __restrict__ offs) {
    __shared__ int lhist[256];
    __shared__ int lexc[256];
    __shared__ int lcur[256];
    int t = threadIdx.x;
    int b = blockIdx.x;
    int sbeg = bbase[b], send = bbase[b + 1];
    lhist[t] = 0;
    __syncthreads();
    for (int i = sbeg + t; i < send; i += 256)
        atomicAdd(&lhist[(staged[i] >> 16) & 255], 1);
    __syncthreads();
    // exclusive scan of lhist
    int v = lhist[t];
    lexc[t] = v;
    for (int off = 1; off < 256; off <<= 1) {
        __syncthreads();
        int x = (t >= off) ? lexc[t - off] : 0;
        __syncthreads();
        lexc[t] += x;
    }
    __syncthreads();
    int excl = lexc[t] - v;
    int node = b * 256 + t;
    if (node < N_NODES) offs[node] = sbeg + excl;
    lcur[t] = excl;
    __syncthreads();
    for (int i = sbeg + t; i < send; i += 256) {
        u32 ent = staged[i];
        int dlow = (ent >> 16) & 255;
        int r = atomicAdd(&lcur[dlow], 1);
        csr[sbeg + r] = (int)(ent & 0xFFFFu);
    }
}

// ---------------- graph start offsets from sorted batch ----------------
__global__ __launch_bounds__(256) void gstart_kernel(const int* __restrict__ batch,
                                                     int* __restrict__ goffs) {
    int n = blockIdx.x * 256 + threadIdx.x;
    if (n >= N_NODES) return;
    if (n == 0) {
        for (int g = 0; g <= batch[0]; ++g) goffs[g] = 0;
    } else {
        int bp = batch[n - 1], bc = batch[n];
        for (int g = bp + 1; g <= bc; ++g) goffs[g] = n;
    }
    if (n == N_NODES - 1) {
        for (int g = batch[n] + 1; g <= N_GRAPHS; ++g) goffs[g] = N_NODES;
    }
}

// =============================================================
// fused gather(fp16) + BN-apply + GIN MLP(fp32) + BN stats, BM=64
// =============================================================
__global__ __launch_bounds__(256) void mlp_gather_kernel(const int* __restrict__ csr_src,
                                                         const int* __restrict__ offs,
                                                         const u32* __restrict__ z_in,
                                                         const float* __restrict__ ss,
                                                         int use_ss,
                                                         u32* __restrict__ z_out,
                                                         const float* __restrict__ W1,
                                                         const float* __restrict__ b1,
                                                         const float* __restrict__ W2,
                                                         const float* __restrict__ b2,
                                                         float* __restrict__ stats) {
    __shared__ float As[64 * 68];    // [k][row], 17.4 KB — reused for t1
    __shared__ float Ws[C * C];      // 16 KB: W1, then W2, then stats-reduce
    int t = threadIdx.x;
    int tc = t & 15, tr = t >> 4;
    for (int i = t; i < C * C; i += 256) Ws[i] = W1[i];
    int row0 = blockIdx.x * 64;

    float4 sc = make_float4(1.f, 1.f, 1.f, 1.f);
    float4 sh = make_float4(0.f, 0.f, 0.f, 0.f);
    if (use_ss) {
        sc = ((const float4*)ss)[tc];
        sh = ((const float4*)(ss + C))[tc];
    }

    // ---- gather + BN-apply, staged transposed into As ----
    const uint2* z2 = (const uint2*)z_in;   // 8 B = 4 fp16 channels
    for (int it = 0; it < 4; ++it) {
        int r = tr + 16 * it;               // 0..63
        int node = row0 + r;
        float4 acc = make_float4(0.f, 0.f, 0.f, 0.f);
        if (node < N_NODES) {
            uint2 sv = z2[node * 16 + tc];  // self term (GIN eps=0)
            float2 f0 = h2f(sv.x), f1 = h2f(sv.y);
            acc.x = f0.x; acc.y = f0.y; acc.z = f1.x; acc.w = f1.y;
            int beg = offs[node], end = offs[node + 1];
            int e = beg;
            for (; e + 3 < end; e += 4) {   // 4 independent line-loads in flight
                int s0 = csr_src[e], s1 = csr_src[e + 1], s2 = csr_src[e + 2], s3 = csr_src[e + 3];
                uint2 v0 = z2[s0 * 16 + tc], v1 = z2[s1 * 16 + tc];
                uint2 v2 = z2[s2 * 16 + tc], v3 = z2[s3 * 16 + tc];
                float2 a0 = h2f(v0.x), a1 = h2f(v1.x), a2 = h2f(v2.x), a3 = h2f(v3.x);
                float2 c0 = h2f(v0.y), c1 = h2f(v1.y), c2 = h2f(v2.y), c3 = h2f(v3.y);
                acc.x += (a0.x + a1.x) + (a2.x + a3.x);
                acc.y += (a0.y + a1.y) + (a2.y + a3.y);
                acc.z += (c0.x + c1.x) + (c2.x + c3.x);
                acc.w += (c0.y + c1.y) + (c2.y + c3.y);
            }
            for (; e < end; ++e) {
                uint2 v = z2[csr_src[e] * 16 + tc];
                float2 a = h2f(v.x), c = h2f(v.y);
                acc.x += a.x; acc.y += a.y; acc.z += c.x; acc.w += c.y;
            }
            float cnt = (float)(end - beg + 1);
            acc.x = fmaf(acc.x, sc.x, cnt * sh.x);
            acc.y = fmaf(acc.y, sc.y, cnt * sh.y);
            acc.z = fmaf(acc.z, sc.z, cnt * sh.z);
            acc.w = fmaf(acc.w, sc.w, cnt * sh.w);
        }
        int k4 = tc * 4;
        As[(k4 + 0) * 68 + r] = acc.x;
        As[(k4 + 1) * 68 + r] = acc.y;
        As[(k4 + 2) * 68 + r] = acc.z;
        As[(k4 + 3) * 68 + r] = acc.w;
    }
    __syncthreads();

    // ---- GEMM1: t1 = relu(y@W1+b1), TM=4 x TN=4 ----
    float4 b1v = ((const float4*)b1)[tc];
    float a[4][4];
#pragma unroll
    for (int i = 0; i < 4; ++i) { a[i][0] = b1v.x; a[i][1] = b1v.y; a[i][2] = b1v.z; a[i][3] = b1v.w; }
#pragma unroll 4
    for (int k = 0; k < 64; ++k) {
        float4 av = *(const float4*)(As + k * 68 + tr * 4);
        float4 w = *(const float4*)(Ws + k * C + tc * 4);
        float avv[4] = {av.x, av.y, av.z, av.w};
#pragma unroll
        for (int i = 0; i < 4; ++i) {
            a[i][0] = fmaf(avv[i], w.x, a[i][0]);
            a[i][1] = fmaf(avv[i], w.y, a[i][1]);
            a[i][2] = fmaf(avv[i], w.z, a[i][2]);
            a[i][3] = fmaf(avv[i], w.w, a[i][3]);
        }
    }
    __syncthreads();  // As + Ws(W1) reads done

    // ---- restage t1^T into As; load W2 ----
#pragma unroll
    for (int i = 0; i < 4; ++i)
#pragma unroll
        for (int j = 0; j < 4; ++j)
            As[(tc * 4 + j) * 68 + tr * 4 + i] = fmaxf(a[i][j], 0.f);
    for (int i = t; i < C * C; i += 256) Ws[i] = W2[i];
    __syncthreads();

    // ---- GEMM2: z = relu(t1@W2+b2) ----
    float4 b2v = ((const float4*)b2)[tc];
#pragma unroll
    for (int i = 0; i < 4; ++i) { a[i][0] = b2v.x; a[i][1] = b2v.y; a[i][2] = b2v.z; a[i][3] = b2v.w; }
#pragma unroll 4
    for (int k = 0; k < 64; ++k) {
        float4 av = *(const float4*)(As + k * 68 + tr * 4);
        float4 w = *(const float4*)(Ws + k * C + tc * 4);
        float avv[4] = {av.x, av.y, av.z, av.w};
#pragma unroll
        for (int i = 0; i < 4; ++i) {
            a[i][0] = fmaf(avv[i], w.x, a[i][0]);
            a[i][1] = fmaf(avv[i], w.y, a[i][1]);
            a[i][2] = fmaf(avv[i], w.z, a[i][2]);
            a[i][3] = fmaf(avv[i], w.w, a[i][3]);
        }
    }

    // ---- relu, fp16 store, local BN stats (fp32, pre-rounding) ----
    float lsum[4] = {0.f, 0.f, 0.f, 0.f};
    float lsq[4] = {0.f, 0.f, 0.f, 0.f};
#pragma unroll
    for (int i = 0; i < 4; ++i) {
        int grow = row0 + tr * 4 + i;
        if (grow < N_NODES) {
            float o0 = fmaxf(a[i][0], 0.f), o1 = fmaxf(a[i][1], 0.f);
            float o2 = fmaxf(a[i][2], 0.f), o3 = fmaxf(a[i][3], 0.f);
            uint2 o;
            o.x = f2h2(o0, o1);
            o.y = f2h2(o2, o3);
            ((uint2*)z_out)[grow * 16 + tc] = o;
            lsum[0] += o0; lsum[1] += o1; lsum[2] += o2; lsum[3] += o3;
            lsq[0] += o0 * o0; lsq[1] += o1 * o1; lsq[2] += o2 * o2; lsq[3] += o3 * o3;
        }
    }
    __syncthreads();  // Ws(W2) reads done; reuse as reduction buffer 16x128
    float* red = Ws;
#pragma unroll
    for (int j = 0; j < 4; ++j) {
        red[tr * 128 + tc * 4 + j] = lsum[j];
        red[tr * 128 + 64 + tc * 4 + j] = lsq[j];
    }
    __syncthreads();
    if (t < 128) {
        float s = 0.f;
#pragma unroll
        for (int r = 0; r < 16; ++r) s += red[r * 128 + t];
        atomicAdd(&stats[t], s);  // [0..63]=sum, [64..127]=sumsq
    }
}

// ---------------- BN finalize ----------------
__global__ void bn_finalize(const float* __restrict__ stats,
                            const float* __restrict__ gamma,
                            const float* __restrict__ beta,
                            float* __restrict__ ss) {
    int c = threadIdx.x;
    if (c >= C) return;
    const float invN = 1.0f / (float)N_NODES;
    float mean = stats[c] * invN;
    float var = stats[C + c] * invN - mean * mean;
    float rstd = rsqrtf(var + BN_EPS);
    float sc = gamma[c] * rstd;
    ss[c] = sc;
    ss[C + c] = beta[c] - mean * sc;
}

// ---------------- pool: segmented reduction over sorted batch, no atomics ----------------
__global__ __launch_bounds__(256) void pool_kernel(const u32* __restrict__ z,
                                                   const float* __restrict__ ss,
                                                   const int* __restrict__ goffs,
                                                   float* __restrict__ g) {
    __shared__ float4 red[256];
    int t = threadIdx.x;
    int tc = t & 15, tr = t >> 4;
    int gr = blockIdx.x;
    int beg = goffs[gr], end = goffs[gr + 1];
    const uint2* z2 = (const uint2*)z;
    float4 acc = make_float4(0.f, 0.f, 0.f, 0.f);
    for (int n = beg + tr; n < end; n += 16) {
        uint2 v = z2[n * 16 + tc];
        float2 a = h2f(v.x), c = h2f(v.y);
        acc.x += a.x; acc.y += a.y; acc.z += c.x; acc.w += c.y;
    }
    red[tr * 16 + tc] = acc;
    for (int s = 8; s > 0; s >>= 1) {
        __syncthreads();
        if (tr < s) {
            float4 o = red[(tr + s) * 16 + tc];
            float4 m = red[tr * 16 + tc];
            m.x += o.x; m.y += o.y; m.z += o.z; m.w += o.w;
            red[tr * 16 + tc] = m;
        }
    }
    __syncthreads();
    if (tr == 0) {
        float4 sum = red[tc];
        float4 sc = ((const float4*)ss)[tc];
        float4 sh = ((const float4*)(ss + C))[tc];
        float cnt = (float)(end - beg);
        float4 o;
        o.x = fmaf(sum.x, sc.x, cnt * sh.x);
        o.y = fmaf(sum.y, sc.y, cnt * sh.y);
        o.z = fmaf(sum.z, sc.z, cnt * sh.z);
        o.w = fmaf(sum.w, sc.w, cnt * sh.w);
        ((float4*)g)[gr * 16 + tc] = o;
    }
}

// ---------------- head ----------------
__global__ __launch_bounds__(256) void head_kernel(const float* __restrict__ g,
                                                   const float* __restrict__ fc1W,
                                                   const float* __restrict__ fc1b,
                                                   const float* __restrict__ fc2W,
                                                   const float* __restrict__ fc2b,
                                                   float* __restrict__ out) {
    __shared__ float W1s[C * C];
    __shared__ float W2s[C * 16];
    __shared__ float gs[4][C], t1s[4][C];
    int t = threadIdx.x;
    for (int i = t; i < C * C; i += 256) W1s[i] = fc1W[i];
    for (int i = t; i < C * 16; i += 256) W2s[i] = fc2W[i];
    int ch = t & 63, rr = t >> 6;
    int g0 = blockIdx.x * 4;
    gs[rr][ch] = g[(g0 + rr) * C + ch];
    __syncthreads();
    float a1 = fc1b[ch];
#pragma unroll 8
    for (int k = 0; k < C; ++k) a1 = fmaf(gs[rr][k], W1s[k * C + ch], a1);
    t1s[rr][ch] = fmaxf(a1, 0.f);
    __syncthreads();
    if (t < 64) {
        int o = t & 15, r2 = t >> 4;
        float a2 = fc2b[o];
#pragma unroll 8
        for (int k = 0; k < C; ++k) a2 = fmaf(t1s[r2][k], W2s[k * 16 + o], a2);
        out[(g0 + r2) * 16 + o] = a2;
    }
}

extern "C" void kernel_launch(void* const* d_in, const int* in_sizes, int n_in,
                              void* d_out, int out_size, void* d_ws, size_t ws_size,
                              hipStream_t stream) {
    const float* x    = (const float*)d_in[0];
    const int*   ei   = (const int*)d_in[1];
    const int*   batch= (const int*)d_in[2];
    const float* encW = (const float*)d_in[3];
    const float* encb = (const float*)d_in[4];
    const float* cW1  = (const float*)d_in[5];
    const float* cb1  = (const float*)d_in[6];
    const float* cW2  = (const float*)d_in[7];
    const float* cb2  = (const float*)d_in[8];
    const float* gam  = (const float*)d_in[9];
    const float* bet  = (const float*)d_in[10];
    const float* f1W  = (const float*)d_in[11];
    const float* f1b  = (const float*)d_in[12];
    const float* f2W  = (const float*)d_in[13];
    const float* f2b  = (const float*)d_in[14];
    float* out = (float*)d_out;

    char* ws = (char*)d_ws;
    u32*   zA      = (u32*)  (ws);                    // fp16: 6.4 MB
    u32*   zB      = (u32*)  (ws + 6400000);          // fp16: 6.4 MB
    int*   csr     = (int*)  (ws + 12800000);         // 3.2 MB
    u32*   staged  = (u32*)  (ws + 16000000);         // 3.2 MB
    int*   offs    = (int*)  (ws + 19200000);         // 50001 ints
    int*   bcount  = (int*)  (ws + 19400064);         // 196 ints
    int*   bbase   = (int*)  (ws + 19401088);         // 197 ints
    int*   bcursor = (int*)  (ws + 19402112);         // 196 ints
    float* stats   = (float*)(ws + 19403136);         // 5*128 floats
    float* ssb     = (float*)(ws + 19405696);         // 5*128 floats
    int*   goffs   = (int*)  (ws + 19408256);         // 513 ints
    float* gpool   = (float*)(ws + 19410432);         // 128 KB

    // --- bucketed CSR build + graph offsets (once per call) ---
    hipMemsetAsync(bcount, 0, NBUCK * sizeof(int), stream);
    hipMemsetAsync(stats, 0, 5 * 2 * C * sizeof(float), stream);
    csr_hist<<<NBUCK, 256, 0, stream>>>(ei, bcount);
    csr_bscan<<<1, 256, 0, stream>>>(bcount, bbase, bcursor, offs);
    csr_stage<<<NBUCK, 256, 0, stream>>>(ei, bcursor, staged);
    csr_finalize<<<NBUCK, 256, 0, stream>>>(staged, bbase, csr, offs);
    gstart_kernel<<<SCAN_BLOCKS, 256, 0, stream>>>(batch, goffs);

    enc_kernel<<<(N_NODES + 127) / 128, 256, 0, stream>>>(x, encW, encb, zA);

    u32* zin = zA;
    u32* zout = zB;
    for (int l = 0; l < N_LAYERS; ++l) {
        const float* ss_prev = (l > 0) ? (ssb + (size_t)(l - 1) * 2 * C) : ssb;
        mlp_gather_kernel<<<(N_NODES + 63) / 64, 256, 0, stream>>>(
            csr, offs, zin, ss_prev, l > 0 ? 1 : 0, zout,
            cW1 + (size_t)l * C * C, cb1 + (size_t)l * C,
            cW2 + (size_t)l * C * C, cb2 + (size_t)l * C,
            stats + (size_t)l * 2 * C);
        bn_finalize<<<1, 64, 0, stream>>>(stats + (size_t)l * 2 * C,
                                          gam + (size_t)l * C, bet + (size_t)l * C,
                                          ssb + (size_t)l * 2 * C);
        u32* tmp = zin; zin = zout; zout = tmp;
    }

    // zin holds layer-5 pre-BN output (fp16); pool applies final BN
    pool_kernel<<<N_GRAPHS, 256, 0, stream>>>(zin, ssb + (size_t)(N_LAYERS - 1) * 2 * C, goffs, gpool);
    head_kernel<<<N_GRAPHS / 4, 256, 0, stream>>>(gpool, f1W, f1b, f2W, f2b, out);
}

// Round 7
// 393.084 us; speedup vs baseline: 10.4501x; 1.1015x over previous
//
#include <hip/hip_runtime.h>
#include <hip/hip_fp16.h>

#define N_NODES 50000
#define N_EDGES 800000
#define NODE_DIM 128
#define C 64
#define N_GRAPHS 512
#define N_LAYERS 5
#define BN_EPS 1e-5f

#define SCAN_BLOCKS 196   // ceil(50000/256)
#define NBUCK 196         // buckets of 256 nodes: bucket = dst >> 8
#define ECHUNK 4096       // edges per block in CSR-build passes

typedef unsigned int u32;
typedef unsigned short u16;

// fp16 helpers: 2 ch per u32 word
__device__ inline float2 h2f(u32 v) {
    __half2 h; __builtin_memcpy(&h, &v, 4);
    return __half22float2(h);
}
__device__ inline u32 f2h2(float a, float b) {
    __half2 h = __floats2half2_rn(a, b);
    u32 v; __builtin_memcpy(&v, &h, 4);
    return v;
}

// =============================================================
// encoder: z = x @ enc_W + enc_b   [50000,128]x[128,64], z stored fp16
// =============================================================
__global__ __launch_bounds__(256) void enc_kernel(const float* __restrict__ x,
                                                  const float* __restrict__ W,
                                                  const float* __restrict__ b,
                                                  u32* __restrict__ z) {
    __shared__ float As[64 * 132];        // [k][row], row-dim padded
    __shared__ float Ws[NODE_DIM * C];    // 32 KB, full K
    int t = threadIdx.x;
    int tc = t & 15, tr = t >> 4;
    for (int i = t; i < NODE_DIM * C; i += 256) Ws[i] = W[i];
    int row0 = blockIdx.x * 128;
    float4 bv = ((const float4*)b)[tc];
    float acc[8][4];
#pragma unroll
    for (int i = 0; i < 8; ++i) { acc[i][0] = bv.x; acc[i][1] = bv.y; acc[i][2] = bv.z; acc[i][3] = bv.w; }

    for (int kc = 0; kc < 2; ++kc) {
        __syncthreads();
        for (int it = 0; it < 8; ++it) {
            int idx = t + 256 * it;
            int r = idx >> 4, f4 = idx & 15;
            int grow = row0 + r;
            float4 v = (grow < N_NODES) ? ((const float4*)x)[grow * 32 + kc * 16 + f4]
                                        : make_float4(0.f, 0.f, 0.f, 0.f);
            int k4 = f4 * 4;
            As[(k4 + 0) * 132 + r] = v.x;
            As[(k4 + 1) * 132 + r] = v.y;
            As[(k4 + 2) * 132 + r] = v.z;
            As[(k4 + 3) * 132 + r] = v.w;
        }
        __syncthreads();
#pragma unroll 4
        for (int k = 0; k < 64; ++k) {
            const float* ap = As + k * 132 + tr * 8;
            float4 a0 = *(const float4*)(ap);
            float4 a1 = *(const float4*)(ap + 4);
            float4 w = *(const float4*)(Ws + (kc * 64 + k) * C + tc * 4);
            float av[8] = {a0.x, a0.y, a0.z, a0.w, a1.x, a1.y, a1.z, a1.w};
#pragma unroll
            for (int i = 0; i < 8; ++i) {
                acc[i][0] = fmaf(av[i], w.x, acc[i][0]);
                acc[i][1] = fmaf(av[i], w.y, acc[i][1]);
                acc[i][2] = fmaf(av[i], w.z, acc[i][2]);
                acc[i][3] = fmaf(av[i], w.w, acc[i][3]);
            }
        }
    }
#pragma unroll
    for (int i = 0; i < 8; ++i) {
        int grow = row0 + tr * 8 + i;
        if (grow < N_NODES) {
            uint2 o;
            o.x = f2h2(acc[i][0], acc[i][1]);
            o.y = f2h2(acc[i][2], acc[i][3]);
            ((uint2*)z)[grow * 16 + tc] = o;
        }
    }
}

// ================= bucketed CSR build =================
__global__ __launch_bounds__(256) void csr_hist(const int* __restrict__ ei,
                                                int* __restrict__ bcount) {
    __shared__ int lhist[NBUCK];
    int t = threadIdx.x;
    if (t < NBUCK) lhist[t] = 0;
    __syncthreads();
    int e0 = blockIdx.x * ECHUNK;
    int e1 = min(e0 + ECHUNK, N_EDGES);
    for (int e = e0 + t; e < e1; e += 256)
        atomicAdd(&lhist[ei[N_EDGES + e] >> 8], 1);
    __syncthreads();
    if (t < NBUCK && lhist[t] > 0) atomicAdd(&bcount[t], lhist[t]);
}

__global__ __launch_bounds__(256) void csr_bscan(const int* __restrict__ bcount,
                                                 int* __restrict__ bbase,
                                                 int* __restrict__ bcursor,
                                                 int* __restrict__ offs) {
    __shared__ int s[256];
    int t = threadIdx.x;
    int v = (t < NBUCK) ? bcount[t] : 0;
    s[t] = v;
    for (int off = 1; off < 256; off <<= 1) {
        __syncthreads();
        int x = (t >= off) ? s[t - off] : 0;
        __syncthreads();
        s[t] += x;
    }
    __syncthreads();
    if (t < NBUCK) {
        bbase[t + 1] = s[t];
        bcursor[t] = s[t] - v;   // exclusive base = cursor seed
    }
    if (t == 0) { bbase[0] = 0; offs[N_NODES] = N_EDGES; }
}

// A2: stage entries bucket-major; entry = src | (dstLow8 << 16)
__global__ __launch_bounds__(256) void csr_stage(const int* __restrict__ ei,
                                                 int* __restrict__ bcursor,
                                                 u32* __restrict__ staged) {
    __shared__ int lhist[NBUCK];
    __shared__ int lbase[NBUCK];
    __shared__ int lcur[NBUCK];
    int t = threadIdx.x;
    if (t < NBUCK) lhist[t] = 0;
    __syncthreads();
    int e0 = blockIdx.x * ECHUNK;
    int e1 = min(e0 + ECHUNK, N_EDGES);
    for (int e = e0 + t; e < e1; e += 256)
        atomicAdd(&lhist[ei[N_EDGES + e] >> 8], 1);
    __syncthreads();
    if (t < NBUCK) {
        int c = lhist[t];
        lbase[t] = (c > 0) ? atomicAdd(&bcursor[t], c) : 0;
        lcur[t] = 0;
    }
    __syncthreads();
    for (int e = e0 + t; e < e1; e += 256) {
        int src = ei[e];
        int dst = ei[N_EDGES + e];
        int bk = dst >> 8;
        int r = atomicAdd(&lcur[bk], 1);
        staged[lbase[bk] + r] = (u32)src | ((u32)(dst & 255) << 16);
    }
}

// B: per-bucket counting sort -> csr (u16) + per-node offs
__global__ __launch_bounds__(256) void csr_finalize(const u32* __restrict__ staged,
                                                    const int* __restrict__ bbase,
                                                    u16* __restrict__ csr,
                                                    int* __restrict__ offs) {
    __shared__ int lhist[256];
    __shared__ int lexc[256];
    __shared__ int lcur[256];
    int t = threadIdx.x;
    int b = blockIdx.x;
    int sbeg = bbase[b], send = bbase[b + 1];
    lhist[t] = 0;
    __syncthreads();
    for (int i = sbeg + t; i < send; i += 256)
        atomicAdd(&lhist[(staged[i] >> 16) & 255], 1);
    __syncthreads();
    int v = lhist[t];
    lexc[t] = v;
    for (int off = 1; off < 256; off <<= 1) {
        __syncthreads();
        int x = (t >= off) ? lexc[t - off] : 0;
        __syncthreads();
        lexc[t] += x;
    }
    __syncthreads();
    int excl = lexc[t] - v;
    int node = b * 256 + t;
    if (node < N_NODES) offs[node] = sbeg + excl;
    lcur[t] = excl;
    __syncthreads();
    for (int i = sbeg + t; i < send; i += 256) {
        u32 ent = staged[i];
        int dlow = (ent >> 16) & 255;
        int r = atomicAdd(&lcur[dlow], 1);
        csr[sbeg + r] = (u16)(ent & 0xFFFFu);
    }
}

// ---------------- graph start offsets from sorted batch ----------------
__global__ __launch_bounds__(256) void gstart_kernel(const int* __restrict__ batch,
                                                     int* __restrict__ goffs) {
    int n = blockIdx.x * 256 + threadIdx.x;
    if (n >= N_NODES) return;
    if (n == 0) {
        for (int g = 0; g <= batch[0]; ++g) goffs[g] = 0;
    } else {
        int bp = batch[n - 1], bc = batch[n];
        for (int g = bp + 1; g <= bc; ++g) goffs[g] = n;
    }
    if (n == N_NODES - 1) {
        for (int g = batch[n] + 1; g <= N_GRAPHS; ++g) goffs[g] = N_NODES;
    }
}

// =============================================================
// fused gather(fp16, uint4 16B/lane) + BN-apply + MLP(fp32, fp16 LDS) + BN stats
// BM=64. LDS: Asw 8.5 KB + Ws 16 KB = 24.5 KB -> 6 blocks/CU.
// Asw layout: u32 [32][68]; word w, row r = channels {2w,2w+1} of row r (fp16x2).
// =============================================================
__global__ __launch_bounds__(256) void mlp_gather_kernel(const u16* __restrict__ csr_src,
                                                         const int* __restrict__ offs,
                                                         const u32* __restrict__ z_in,
                                                         const float* __restrict__ ss,
                                                         int use_ss,
                                                         u32* __restrict__ z_out,
                                                         const float* __restrict__ W1,
                                                         const float* __restrict__ b1,
                                                         const float* __restrict__ W2,
                                                         const float* __restrict__ b2,
                                                         float* __restrict__ stats) {
    __shared__ u32 Asw[32 * 68];     // 8.5 KB, fp16-packed [word][row]
    __shared__ float Ws[C * C];      // 16 KB: W1, then W2, then stats-reduce
    int t = threadIdx.x;
    int tc = t & 15, tr = t >> 4;
    for (int i = t; i < C * C; i += 256) Ws[i] = W1[i];
    int row0 = blockIdx.x * 64;

    // ---- gather: 8 lanes per row, uint4 = 8 fp16 channels per lane ----
    int tg = t & 7;         // channel-group: ch tg*8 .. +7
    int rg = t >> 3;        // 0..31
    float scv[8], shv[8];
    if (use_ss) {
        float4 s0 = ((const float4*)ss)[tg * 2], s1 = ((const float4*)ss)[tg * 2 + 1];
        float4 h0 = ((const float4*)(ss + C))[tg * 2], h1 = ((const float4*)(ss + C))[tg * 2 + 1];
        scv[0] = s0.x; scv[1] = s0.y; scv[2] = s0.z; scv[3] = s0.w;
        scv[4] = s1.x; scv[5] = s1.y; scv[6] = s1.z; scv[7] = s1.w;
        shv[0] = h0.x; shv[1] = h0.y; shv[2] = h0.z; shv[3] = h0.w;
        shv[4] = h1.x; shv[5] = h1.y; shv[6] = h1.z; shv[7] = h1.w;
    } else {
#pragma unroll
        for (int i = 0; i < 8; ++i) { scv[i] = 1.f; shv[i] = 0.f; }
    }
    const uint4* z4 = (const uint4*)z_in;   // row = 8 uint4
#pragma unroll
    for (int it = 0; it < 2; ++it) {
        int r = rg + 32 * it;
        int node = row0 + r;
        float acc[8] = {0.f, 0.f, 0.f, 0.f, 0.f, 0.f, 0.f, 0.f};
        if (node < N_NODES) {
            uint4 sv = z4[node * 8 + tg];   // self term
            {
                float2 p0 = h2f(sv.x), p1 = h2f(sv.y), p2 = h2f(sv.z), p3 = h2f(sv.w);
                acc[0] = p0.x; acc[1] = p0.y; acc[2] = p1.x; acc[3] = p1.y;
                acc[4] = p2.x; acc[5] = p2.y; acc[6] = p3.x; acc[7] = p3.y;
            }
            int beg = offs[node], end = offs[node + 1];
            int e = beg;
            for (; e + 3 < end; e += 4) {   // 4 independent 16B line-loads in flight
                int s0 = csr_src[e], s1 = csr_src[e + 1], s2 = csr_src[e + 2], s3 = csr_src[e + 3];
                uint4 v0 = z4[s0 * 8 + tg], v1 = z4[s1 * 8 + tg];
                uint4 v2 = z4[s2 * 8 + tg], v3 = z4[s3 * 8 + tg];
                float2 a0 = h2f(v0.x), a1 = h2f(v1.x), a2 = h2f(v2.x), a3 = h2f(v3.x);
                acc[0] += (a0.x + a1.x) + (a2.x + a3.x);
                acc[1] += (a0.y + a1.y) + (a2.y + a3.y);
                a0 = h2f(v0.y); a1 = h2f(v1.y); a2 = h2f(v2.y); a3 = h2f(v3.y);
                acc[2] += (a0.x + a1.x) + (a2.x + a3.x);
                acc[3] += (a0.y + a1.y) + (a2.y + a3.y);
                a0 = h2f(v0.z); a1 = h2f(v1.z); a2 = h2f(v2.z); a3 = h2f(v3.z);
                acc[4] += (a0.x + a1.x) + (a2.x + a3.x);
                acc[5] += (a0.y + a1.y) + (a2.y + a3.y);
                a0 = h2f(v0.w); a1 = h2f(v1.w); a2 = h2f(v2.w); a3 = h2f(v3.w);
                acc[6] += (a0.x + a1.x) + (a2.x + a3.x);
                acc[7] += (a0.y + a1.y) + (a2.y + a3.y);
            }
            for (; e < end; ++e) {
                uint4 v = z4[csr_src[e] * 8 + tg];
                float2 a0 = h2f(v.x), a1 = h2f(v.y), a2 = h2f(v.z), a3 = h2f(v.w);
                acc[0] += a0.x; acc[1] += a0.y; acc[2] += a1.x; acc[3] += a1.y;
                acc[4] += a2.x; acc[5] += a2.y; acc[6] += a3.x; acc[7] += a3.y;
            }
            float cnt = (float)(end - beg + 1);
#pragma unroll
            for (int i = 0; i < 8; ++i) acc[i] = fmaf(acc[i], scv[i], cnt * shv[i]);
        }
        Asw[(tg * 4 + 0) * 68 + r] = f2h2(acc[0], acc[1]);
        Asw[(tg * 4 + 1) * 68 + r] = f2h2(acc[2], acc[3]);
        Asw[(tg * 4 + 2) * 68 + r] = f2h2(acc[4], acc[5]);
        Asw[(tg * 4 + 3) * 68 + r] = f2h2(acc[6], acc[7]);
    }
    __syncthreads();

    // ---- GEMM1: t1 = relu(y@W1+b1), TM=4 x TN=4 ----
    float4 b1v = ((const float4*)b1)[tc];
    float a[4][4];
#pragma unroll
    for (int i = 0; i < 4; ++i) { a[i][0] = b1v.x; a[i][1] = b1v.y; a[i][2] = b1v.z; a[i][3] = b1v.w; }
#pragma unroll 2
    for (int w = 0; w < 32; ++w) {
        uint4 aw = *(const uint4*)(Asw + w * 68 + tr * 4);  // rows tr*4..+3, ch {2w,2w+1}
        float2 r0 = h2f(aw.x), r1 = h2f(aw.y), r2 = h2f(aw.z), r3 = h2f(aw.w);
        float4 w0 = *(const float4*)(Ws + (2 * w) * C + tc * 4);
        float4 w1 = *(const float4*)(Ws + (2 * w + 1) * C + tc * 4);
        float e0[4] = {r0.x, r1.x, r2.x, r3.x};
        float e1[4] = {r0.y, r1.y, r2.y, r3.y};
#pragma unroll
        for (int i = 0; i < 4; ++i) {
            a[i][0] = fmaf(e0[i], w0.x, a[i][0]); a[i][0] = fmaf(e1[i], w1.x, a[i][0]);
            a[i][1] = fmaf(e0[i], w0.y, a[i][1]); a[i][1] = fmaf(e1[i], w1.y, a[i][1]);
            a[i][2] = fmaf(e0[i], w0.z, a[i][2]); a[i][2] = fmaf(e1[i], w1.z, a[i][2]);
            a[i][3] = fmaf(e0[i], w0.w, a[i][3]); a[i][3] = fmaf(e1[i], w1.w, a[i][3]);
        }
    }
    __syncthreads();  // Asw + Ws(W1) reads done

    // ---- restage t1^T (fp16) into Asw; load W2 ----
    {
        uint4 w0, w1;
        w0.x = f2h2(fmaxf(a[0][0], 0.f), fmaxf(a[0][1], 0.f));
        w0.y = f2h2(fmaxf(a[1][0], 0.f), fmaxf(a[1][1], 0.f));
        w0.z = f2h2(fmaxf(a[2][0], 0.f), fmaxf(a[2][1], 0.f));
        w0.w = f2h2(fmaxf(a[3][0], 0.f), fmaxf(a[3][1], 0.f));
        w1.x = f2h2(fmaxf(a[0][2], 0.f), fmaxf(a[0][3], 0.f));
        w1.y = f2h2(fmaxf(a[1][2], 0.f), fmaxf(a[1][3], 0.f));
        w1.z = f2h2(fmaxf(a[2][2], 0.f), fmaxf(a[2][3], 0.f));
        w1.w = f2h2(fmaxf(a[3][2], 0.f), fmaxf(a[3][3], 0.f));
        *(uint4*)(Asw + (tc * 2) * 68 + tr * 4) = w0;       // ch pair {tc*4, tc*4+1}
        *(uint4*)(Asw + (tc * 2 + 1) * 68 + tr * 4) = w1;   // ch pair {tc*4+2, tc*4+3}
    }
    for (int i = t; i < C * C; i += 256) Ws[i] = W2[i];
    __syncthreads();

    // ---- GEMM2: z = relu(t1@W2+b2) ----
    float4 b2v = ((const float4*)b2)[tc];
#pragma unroll
    for (int i = 0; i < 4; ++i) { a[i][0] = b2v.x; a[i][1] = b2v.y; a[i][2] = b2v.z; a[i][3] = b2v.w; }
#pragma unroll 2
    for (int w = 0; w < 32; ++w) {
        uint4 aw = *(const uint4*)(Asw + w * 68 + tr * 4);
        float2 r0 = h2f(aw.x), r1 = h2f(aw.y), r2 = h2f(aw.z), r3 = h2f(aw.w);
        float4 w0 = *(const float4*)(Ws + (2 * w) * C + tc * 4);
        float4 w1 = *(const float4*)(Ws + (2 * w + 1) * C + tc * 4);
        float e0[4] = {r0.x, r1.x, r2.x, r3.x};
        float e1[4] = {r0.y, r1.y, r2.y, r3.y};
#pragma unroll
        for (int i = 0; i < 4; ++i) {
            a[i][0] = fmaf(e0[i], w0.x, a[i][0]); a[i][0] = fmaf(e1[i], w1.x, a[i][0]);
            a[i][1] = fmaf(e0[i], w0.y, a[i][1]); a[i][1] = fmaf(e1[i], w1.y, a[i][1]);
            a[i][2] = fmaf(e0[i], w0.z, a[i][2]); a[i][2] = fmaf(e1[i], w1.z, a[i][2]);
            a[i][3] = fmaf(e0[i], w0.w, a[i][3]); a[i][3] = fmaf(e1[i], w1.w, a[i][3]);
        }
    }

    // ---- relu, fp16 store, local BN stats (fp32) ----
    float lsum[4] = {0.f, 0.f, 0.f, 0.f};
    float lsq[4] = {0.f, 0.f, 0.f, 0.f};
#pragma unroll
    for (int i = 0; i < 4; ++i) {
        int grow = row0 + tr * 4 + i;
        if (grow < N_NODES) {
            float o0 = fmaxf(a[i][0], 0.f), o1 = fmaxf(a[i][1], 0.f);
            float o2 = fmaxf(a[i][2], 0.f), o3 = fmaxf(a[i][3], 0.f);
            uint2 o;
            o.x = f2h2(o0, o1);
            o.y = f2h2(o2, o3);
            ((uint2*)z_out)[grow * 16 + tc] = o;
            lsum[0] += o0; lsum[1] += o1; lsum[2] += o2; lsum[3] += o3;
            lsq[0] += o0 * o0; lsq[1] += o1 * o1; lsq[2] += o2 * o2; lsq[3] += o3 * o3;
        }
    }
    __syncthreads();  // Ws(W2) reads done; reuse as reduction buffer 16x128
    float* red = Ws;
#pragma unroll
    for (int j = 0; j < 4; ++j) {
        red[tr * 128 + tc * 4 + j] = lsum[j];
        red[tr * 128 + 64 + tc * 4 + j] = lsq[j];
    }
    __syncthreads();
    if (t < 128) {
        float s = 0.f;
#pragma unroll
        for (int r = 0; r < 16; ++r) s += red[r * 128 + t];
        atomicAdd(&stats[t], s);  // [0..63]=sum, [64..127]=sumsq
    }
}

// ---------------- BN finalize ----------------
__global__ void bn_finalize(const float* __restrict__ stats,
                            const float* __restrict__ gamma,
                            const float* __restrict__ beta,
                            float* __restrict__ ss) {
    int c = threadIdx.x;
    if (c >= C) return;
    const float invN = 1.0f / (float)N_NODES;
    float mean = stats[c] * invN;
    float var = stats[C + c] * invN - mean * mean;
    float rstd = rsqrtf(var + BN_EPS);
    float sc = gamma[c] * rstd;
    ss[c] = sc;
    ss[C + c] = beta[c] - mean * sc;
}

// ---------------- pool: segmented reduction over sorted batch ----------------
__global__ __launch_bounds__(256) void pool_kernel(const u32* __restrict__ z,
                                                   const float* __restrict__ ss,
                                                   const int* __restrict__ goffs,
                                                   float* __restrict__ g) {
    __shared__ float4 red[256];
    int t = threadIdx.x;
    int tc = t & 15, tr = t >> 4;
    int gr = blockIdx.x;
    int beg = goffs[gr], end = goffs[gr + 1];
    const uint2* z2 = (const uint2*)z;
    float4 acc = make_float4(0.f, 0.f, 0.f, 0.f);
    for (int n = beg + tr; n < end; n += 16) {
        uint2 v = z2[n * 16 + tc];
        float2 a = h2f(v.x), c = h2f(v.y);
        acc.x += a.x; acc.y += a.y; acc.z += c.x; acc.w += c.y;
    }
    red[tr * 16 + tc] = acc;
    for (int s = 8; s > 0; s >>= 1) {
        __syncthreads();
        if (tr < s) {
            float4 o = red[(tr + s) * 16 + tc];
            float4 m = red[tr * 16 + tc];
            m.x += o.x; m.y += o.y; m.z += o.z; m.w += o.w;
            red[tr * 16 + tc] = m;
        }
    }
    __syncthreads();
    if (tr == 0) {
        float4 sum = red[tc];
        float4 sc = ((const float4*)ss)[tc];
        float4 sh = ((const float4*)(ss + C))[tc];
        float cnt = (float)(end - beg);
        float4 o;
        o.x = fmaf(sum.x, sc.x, cnt * sh.x);
        o.y = fmaf(sum.y, sc.y, cnt * sh.y);
        o.z = fmaf(sum.z, sc.z, cnt * sh.z);
        o.w = fmaf(sum.w, sc.w, cnt * sh.w);
        ((float4*)g)[gr * 16 + tc] = o;
    }
}

// ---------------- head ----------------
__global__ __launch_bounds__(256) void head_kernel(const float* __restrict__ g,
                                                   const float* __restrict__ fc1W,
                                                   const float* __restrict__ fc1b,
                                                   const float* __restrict__ fc2W,
                                                   const float* __restrict__ fc2b,
                                                   float* __restrict__ out) {
    __shared__ float W1s[C * C];
    __shared__ float W2s[C * 16];
    __shared__ float gs[4][C], t1s[4][C];
    int t = threadIdx.x;
    for (int i = t; i < C * C; i += 256) W1s[i] = fc1W[i];
    for (int i = t; i < C * 16; i += 256) W2s[i] = fc2W[i];
    int ch = t & 63, rr = t >> 6;
    int g0 = blockIdx.x * 4;
    gs[rr][ch] = g[(g0 + rr) * C + ch];
    __syncthreads();
    float a1 = fc1b[ch];
#pragma unroll 8
    for (int k = 0; k < C; ++k) a1 = fmaf(gs[rr][k], W1s[k * C + ch], a1);
    t1s[rr][ch] = fmaxf(a1, 0.f);
    __syncthreads();
    if (t < 64) {
        int o = t & 15, r2 = t >> 4;
        float a2 = fc2b[o];
#pragma unroll 8
        for (int k = 0; k < C; ++k) a2 = fmaf(t1s[r2][k], W2s[k * 16 + o], a2);
        out[(g0 + r2) * 16 + o] = a2;
    }
}

extern "C" void kernel_launch(void* const* d_in, const int* in_sizes, int n_in,
                              void* d_out, int out_size, void* d_ws, size_t ws_size,
                              hipStream_t stream) {
    const float* x    = (const float*)d_in[0];
    const int*   ei   = (const int*)d_in[1];
    const int*   batch= (const int*)d_in[2];
    const float* encW = (const float*)d_in[3];
    const float* encb = (const float*)d_in[4];
    const float* cW1  = (const float*)d_in[5];
    const float* cb1  = (const float*)d_in[6];
    const float* cW2  = (const float*)d_in[7];
    const float* cb2  = (const float*)d_in[8];
    const float* gam  = (const float*)d_in[9];
    const float* bet  = (const float*)d_in[10];
    const float* f1W  = (const float*)d_in[11];
    const float* f1b  = (const float*)d_in[12];
    const float* f2W  = (const float*)d_in[13];
    const float* f2b  = (const float*)d_in[14];
    float* out = (float*)d_out;

    char* ws = (char*)d_ws;
    u32*   zA      = (u32*)  (ws);                    // fp16: 6.4 MB
    u32*   zB      = (u32*)  (ws + 6400000);          // fp16: 6.4 MB
    u16*   csr     = (u16*)  (ws + 12800000);         // 1.6 MB
    u32*   staged  = (u32*)  (ws + 16000000);         // 3.2 MB
    int*   offs    = (int*)  (ws + 19200000);         // 50001 ints
    int*   bcount  = (int*)  (ws + 19400064);         // 196 ints
    int*   bbase   = (int*)  (ws + 19401088);         // 197 ints
    int*   bcursor = (int*)  (ws + 19402112);         // 196 ints
    float* stats   = (float*)(ws + 19403136);         // 5*128 floats
    float* ssb     = (float*)(ws + 19405696);         // 5*128 floats
    int*   goffs   = (int*)  (ws + 19408256);         // 513 ints
    float* gpool   = (float*)(ws + 19410432);         // 128 KB

    // --- bucketed CSR build + graph offsets (once per call) ---
    hipMemsetAsync(bcount, 0, NBUCK * sizeof(int), stream);
    hipMemsetAsync(stats, 0, 5 * 2 * C * sizeof(float), stream);
    csr_hist<<<NBUCK, 256, 0, stream>>>(ei, bcount);
    csr_bscan<<<1, 256, 0, stream>>>(bcount, bbase, bcursor, offs);
    csr_stage<<<NBUCK, 256, 0, stream>>>(ei, bcursor, staged);
    csr_finalize<<<NBUCK, 256, 0, stream>>>(staged, bbase, csr, offs);
    gstart_kernel<<<SCAN_BLOCKS, 256, 0, stream>>>(batch, goffs);

    enc_kernel<<<(N_NODES + 127) / 128, 256, 0, stream>>>(x, encW, encb, zA);

    u32* zin = zA;
    u32* zout = zB;
    for (int l = 0; l < N_LAYERS; ++l) {
        const float* ss_prev = (l > 0) ? (ssb + (size_t)(l - 1) * 2 * C) : ssb;
        mlp_gather_kernel<<<(N_NODES + 63) / 64, 256, 0, stream>>>(
            csr, offs, zin, ss_prev, l > 0 ? 1 : 0, zout,
            cW1 + (size_t)l * C * C, cb1 + (size_t)l * C,
            cW2 + (size_t)l * C * C, cb2 + (size_t)l * C,
            stats + (size_t)l * 2 * C);
        bn_finalize<<<1, 64, 0, stream>>>(stats + (size_t)l * 2 * C,
                                          gam + (size_t)l * C, bet + (size_t)l * C,
                                          ssb + (size_t)l * 2 * C);
        u32* tmp = zin; zin = zout; zout = tmp;
    }

    // zin holds layer-5 pre-BN output (fp16); pool applies final BN
    pool_kernel<<<N_GRAPHS, 256, 0, stream>>>(zin, ssb + (size_t)(N_LAYERS - 1) * 2 * C, goffs, gpool);
    head_kernel<<<N_GRAPHS / 4, 256, 0, stream>>>(gpool, f1W, f1b, f2W, f2b, out);
}